// Round 9
// baseline (368.726 us; speedup 1.0000x reference)
//
#include <hip/hip_runtime.h>
#include <hip/hip_bf16.h>
#include <math.h>

#define BATCH 2
#define CDIM 128
#define SS 16
#define HH_ 32
#define WW_ 32
#define NSP (SS*HH_*WW_)
#define GS 8
#define GH 16
#define GW 16
#define GN (GS*GH*GW)
#define HEADS 8
#define DH 16
#define NW 256
#define W3L 64
#define W3G 8
#define TOPK 4
#define W3 (W3L + TOPK*W3G)
#define LN_EPS 1e-6f
#define ROUTE_SCALE 0.08838834764831845f
#define GATTN_SCALE 0.25f

typedef short bshort8 __attribute__((ext_vector_type(8)));
typedef float f32x4 __attribute__((ext_vector_type(4)));

__device__ __forceinline__ unsigned short f2bf(float f) {
    unsigned int u = __float_as_uint(f);
    unsigned int r = (u + 0x7fffu + ((u >> 16) & 1u)) >> 16;
    return (unsigned short)r;
}
__device__ __forceinline__ float bf2f_lo(unsigned int u) { return __uint_as_float(u << 16); }
__device__ __forceinline__ float bf2f_hi(unsigned int u) { return __uint_as_float(u & 0xffff0000u); }

__device__ __forceinline__ float gelu_exact(float x) {
    return 0.5f * x * (1.0f + erff(x * 0.70710678118654752f));
}

__device__ __forceinline__ float shfl_sum32(float v) {
#pragma unroll
    for (int m = 16; m > 0; m >>= 1) v += __shfl_xor(v, m);
    return v;
}
__device__ __forceinline__ float shfl_sum16(float v) {
#pragma unroll
    for (int m = 8; m > 0; m >>= 1) v += __shfl_xor(v, m);
    return v;
}
__device__ __forceinline__ float shfl_sum8(float v) {
#pragma unroll
    for (int m = 4; m > 0; m >>= 1) v += __shfl_xor(v, m);
    return v;
}

// swizzled LDS read: layout stores col-group g (8 shorts) of row at group (g ^ (row&7))
__device__ __forceinline__ bshort8 lds_swz(const unsigned short* S, int row, int g) {
    int sg = g ^ (row & 7);
    return *(const bshort8*)&S[row * 128 + sg * 8];
}

// ---------------- K0: ALL weight prep in one kernel ----------------
__global__ __launch_bounds__(256) void k_wprep_all(const float* __restrict__ gqkv_w,
        const float* __restrict__ m2_w1, const float* __restrict__ m2_w2,
        const float* __restrict__ proj_w, const float* __restrict__ mlp_w1,
        const float* __restrict__ mlp_w2, const float* __restrict__ wo_w,
        unsigned short* __restrict__ wt, unsigned short* __restrict__ w1t,
        unsigned short* __restrict__ w2t, unsigned short* __restrict__ projt,
        unsigned short* __restrict__ gw1t, unsigned short* __restrict__ gw2t,
        unsigned short* __restrict__ wot) {
    int id = blockIdx.x * 256 + threadIdx.x;   // 0..344063
    if (id < 49152) {
        int n = id >> 7, k = id & 127;
        float v = gqkv_w[k * 384 + n];
        if (n < 128) v *= ROUTE_SCALE;
        wt[id] = f2bf(v);
    } else if (id < 114688) {
        int i = id - 49152; int n = i >> 7, k = i & 127;
        w1t[i] = f2bf(m2_w1[k * 512 + n]);
    } else if (id < 180224) {
        int i = id - 114688; int n = i >> 9, k = i & 511;
        w2t[i] = f2bf(m2_w2[k * 128 + n]);
    } else if (id < 196608) {
        int i = id - 180224; int n = i >> 7, k = i & 127;
        projt[i] = f2bf(proj_w[k * 128 + n]);
    } else if (id < 262144) {
        int i = id - 196608; int n = i >> 7, k = i & 127;
        gw1t[i] = f2bf(mlp_w1[k * 512 + n]);
    } else if (id < 327680) {
        int i = id - 262144; int n = i >> 9, k = i & 511;
        gw2t[i] = f2bf(mlp_w2[k * 128 + n]);
    } else {
        int i = id - 327680; int n = i >> 7, k = i & 127;
        wot[i] = f2bf(wo_w[k * 128 + n]);
    }
}

// ---------------- K1: global branch qkv (T=8 tokens/block), bf16 q/k/v^T out ----------------
__global__ __launch_bounds__(256) void k_gqkv2(const float* __restrict__ xg_in,
        const float* __restrict__ qkv_w, const float* __restrict__ qkv_b,
        const float* __restrict__ ln_g, const float* __restrict__ ln_b,
        float* __restrict__ xg, unsigned short* __restrict__ qgb,
        unsigned short* __restrict__ kgb, unsigned short* __restrict__ vgtb) {
    int blk = blockIdx.x; int b = blk >> 8; int n0 = (blk & 255) * 8;
    int t = threadIdx.x;
    __shared__ float xs[8][128];
    __shared__ float h[8][128];
    {
        int c = t >> 1, q4 = (t & 1) * 4;
        float4 v = *(const float4*)(xg_in + ((size_t)(b * 128 + c)) * GN + n0 + q4);
        xs[q4 + 0][c] = v.x; xs[q4 + 1][c] = v.y; xs[q4 + 2][c] = v.z; xs[q4 + 3][c] = v.w;
    }
    __syncthreads();
    int j = t >> 5, c4 = (t & 31) * 4;
    float4 v = *(float4*)&xs[j][c4];
    *(float4*)(xg + ((size_t)(b * GN) + n0 + j) * 128 + c4) = v;
    float s1 = shfl_sum32(v.x + v.y + v.z + v.w);
    float mu = s1 * (1.0f / 128.0f);
    float d0 = v.x - mu, d1 = v.y - mu, d2 = v.z - mu, d3 = v.w - mu;
    float s2 = shfl_sum32(d0 * d0 + d1 * d1 + d2 * d2 + d3 * d3);
    float rs = rsqrtf(s2 * (1.0f / 128.0f) + LN_EPS);
    float4 g4 = *(const float4*)(ln_g + c4);
    float4 b4 = *(const float4*)(ln_b + c4);
    float4 hn = { d0 * rs * g4.x + b4.x, d1 * rs * g4.y + b4.y,
                  d2 * rs * g4.z + b4.z, d3 * rs * g4.w + b4.w };
    *(float4*)&h[j][c4] = hn;
    __syncthreads();
    for (int c = t; c < 384; c += 256) {
        float acc[8];
        float bias = qkv_b[c];
#pragma unroll
        for (int jj = 0; jj < 8; jj++) acc[jj] = bias;
        for (int k = 0; k < 128; k++) {
            float w = qkv_w[k * 384 + c];
#pragma unroll
            for (int jj = 0; jj < 8; jj++) acc[jj] = fmaf(h[jj][k], w, acc[jj]);
        }
        int part = c >> 7, head = (c >> 4) & 7, d = c & 15;
        int bh = b * HEADS + head;
        if (part == 0) {
#pragma unroll
            for (int jj = 0; jj < 8; jj++)
                qgb[((size_t)bh * GN + n0 + jj) * DH + d] = f2bf(acc[jj] * GATTN_SCALE);
        } else if (part == 1) {
#pragma unroll
            for (int jj = 0; jj < 8; jj++)
                kgb[((size_t)bh * GN + n0 + jj) * DH + d] = f2bf(acc[jj]);
        } else {
            ushort4 u0, u1;
            u0.x = f2bf(acc[0]); u0.y = f2bf(acc[1]); u0.z = f2bf(acc[2]); u0.w = f2bf(acc[3]);
            u1.x = f2bf(acc[4]); u1.y = f2bf(acc[5]); u1.z = f2bf(acc[6]); u1.w = f2bf(acc[7]);
            unsigned short* dst = vgtb + ((size_t)bh * DH + d) * GN + n0;
            *(ushort4*)dst = u0; *(ushort4*)(dst + 4) = u1;
        }
    }
}

// ---------------- K2: global attention via MFMA bf16 ----------------
__global__ __launch_bounds__(256) void k_gattn_mfma(const unsigned short* __restrict__ qgb,
        const unsigned short* __restrict__ kgb, const unsigned short* __restrict__ vgtb,
        float* __restrict__ og) {
    int blk = blockIdx.x;
    int bh = blk >> 7; int qt = (blk & 127) << 4;
    int b = bh >> 3, hh = bh & 7;
    int t = threadIdx.x; int w = t >> 6; int lane = t & 63;
    int col = lane & 15, quad = lane >> 4;
    __shared__ __align__(16) unsigned short Pbuf[4 * 16 * 40];
    __shared__ float po[4][64][4];
    __shared__ float pl[4][64][4];

    bshort8 aq = {0, 0, 0, 0, 0, 0, 0, 0};
    if (quad < 2)
        aq = *(const bshort8*)(qgb + ((size_t)bh * GN + qt + col) * DH + quad * 8);

    f32x4 o = {0.f, 0.f, 0.f, 0.f};
    float lsum[4] = {0.f, 0.f, 0.f, 0.f};
    const unsigned short* kb = kgb + (size_t)bh * GN * DH;
    const unsigned short* vb = vgtb + (size_t)bh * DH * GN;
    unsigned short* pb = Pbuf + w * (16 * 40);
    int row0 = quad * 4;
    int kbeg = w * 512;
    for (int kc = kbeg; kc < kbeg + 512; kc += 32) {
        bshort8 bk0 = {0, 0, 0, 0, 0, 0, 0, 0};
        bshort8 bk1 = {0, 0, 0, 0, 0, 0, 0, 0};
        if (quad < 2) {
            bk0 = *(const bshort8*)(kb + (size_t)(kc + col) * DH + quad * 8);
            bk1 = *(const bshort8*)(kb + (size_t)(kc + 16 + col) * DH + quad * 8);
        }
        f32x4 z = {0.f, 0.f, 0.f, 0.f};
        f32x4 s0 = __builtin_amdgcn_mfma_f32_16x16x32_bf16(aq, bk0, z, 0, 0, 0);
        f32x4 s1 = __builtin_amdgcn_mfma_f32_16x16x32_bf16(aq, bk1, z, 0, 0, 0);
        float p0[4], p1[4];
#pragma unroll
        for (int r = 0; r < 4; r++) {
            p0[r] = __expf(s0[r]); p1[r] = __expf(s1[r]);
            lsum[r] += p0[r] + p1[r];
        }
#pragma unroll
        for (int r = 0; r < 4; r++) {
            pb[(row0 + r) * 40 + col] = f2bf(p0[r]);
            pb[(row0 + r) * 40 + 16 + col] = f2bf(p1[r]);
        }
        bshort8 pA = *(const bshort8*)(pb + col * 40 + quad * 8);
        bshort8 bv = *(const bshort8*)(vb + (size_t)col * GN + kc + quad * 8);
        o = __builtin_amdgcn_mfma_f32_16x16x32_bf16(pA, bv, o, 0, 0, 0);
    }
#pragma unroll
    for (int r = 0; r < 4; r++) {
        float v = lsum[r];
        v += __shfl_xor(v, 1); v += __shfl_xor(v, 2);
        v += __shfl_xor(v, 4); v += __shfl_xor(v, 8);
        lsum[r] = v;
    }
#pragma unroll
    for (int r = 0; r < 4; r++) { po[w][lane][r] = o[r]; pl[w][lane][r] = lsum[r]; }
    __syncthreads();
    if (w == 0) {
#pragma unroll
        for (int r = 0; r < 4; r++) {
            float os = po[0][lane][r] + po[1][lane][r] + po[2][lane][r] + po[3][lane][r];
            float ls = pl[0][lane][r] + pl[1][lane][r] + pl[2][lane][r] + pl[3][lane][r];
            og[((size_t)(b * GN) + qt + quad * 4 + r) * 128 + hh * 16 + col] = os / ls;
        }
    }
}

// ---------------- K3: global proj+residual+LN+MLP via MFMA, 16 tokens/block ----------------
__global__ __launch_bounds__(256) void k_gmlp_mfma(const float* __restrict__ og,
        const float* __restrict__ xg,
        const unsigned short* __restrict__ projt, const float* __restrict__ proj_b,
        const float* __restrict__ ln_g, const float* __restrict__ ln_b,
        const unsigned short* __restrict__ gw1t, const float* __restrict__ b1,
        const unsigned short* __restrict__ gw2t, const float* __restrict__ b2,
        float* __restrict__ xg4, float* __restrict__ gout) {
    int blk = blockIdx.x; int b = blk >> 7; int n0g = (blk & 127) * 16;
    int t = threadIdx.x; int w = t >> 6; int lane = t & 63;
    int l15 = lane & 15, quad = lane >> 4;
    __shared__ __align__(16) unsigned short ao[16 * 136];
    __shared__ __align__(16) float xs[16 * 132];
    __shared__ __align__(16) unsigned short h[16 * 136];
    __shared__ __align__(16) unsigned short h1[16 * 520];
    float* of32 = (float*)h1;
    f32x4 zero4 = {0.f, 0.f, 0.f, 0.f};

    {
        int j = t >> 4, p = t & 15, c0 = p * 8;
        size_t base = ((size_t)(b * GN) + n0g + j) * 128 + c0;
        float4 v0 = *(const float4*)(og + base);
        float4 v1 = *(const float4*)(og + base + 4);
        ushort4 u0 = { f2bf(v0.x), f2bf(v0.y), f2bf(v0.z), f2bf(v0.w) };
        ushort4 u1 = { f2bf(v1.x), f2bf(v1.y), f2bf(v1.z), f2bf(v1.w) };
        *(ushort4*)&ao[j * 136 + c0] = u0;
        *(ushort4*)&ao[j * 136 + c0 + 4] = u1;
        *(float4*)&xs[j * 132 + c0] = *(const float4*)(xg + base);
        *(float4*)&xs[j * 132 + c0 + 4] = *(const float4*)(xg + base + 4);
    }
    __syncthreads();

    {
        bshort8 a[4];
#pragma unroll
        for (int ks = 0; ks < 4; ks++)
            a[ks] = *(const bshort8*)(ao + l15 * 136 + ks * 32 + quad * 8);
#pragma unroll
        for (int nt = 0; nt < 2; nt++) {
            int n0 = w * 32 + nt * 16;
            f32x4 acc = zero4;
#pragma unroll
            for (int ks = 0; ks < 4; ks++) {
                bshort8 bfr = *(const bshort8*)(projt + (n0 + l15) * 128 + ks * 32 + quad * 8);
                acc = __builtin_amdgcn_mfma_f32_16x16x32_bf16(a[ks], bfr, acc, 0, 0, 0);
            }
            float bias = proj_b[n0 + l15];
#pragma unroll
            for (int r = 0; r < 4; r++) {
                int m = quad * 4 + r;
                xs[m * 132 + n0 + l15] += acc[r] + bias;
            }
        }
    }
    __syncthreads();

    {
        int j = t >> 4, p = t & 15, c0 = p * 8;
        float vv[8]; float s1 = 0.f;
#pragma unroll
        for (int i = 0; i < 8; i++) { vv[i] = xs[j * 132 + c0 + i]; s1 += vv[i]; }
        s1 = shfl_sum16(s1);
        float mu = s1 * (1.0f / 128.0f);
        float s2 = 0.f;
#pragma unroll
        for (int i = 0; i < 8; i++) { float d = vv[i] - mu; s2 += d * d; }
        s2 = shfl_sum16(s2);
        float rs = rsqrtf(s2 * (1.0f / 128.0f) + LN_EPS);
        unsigned short hb[8];
#pragma unroll
        for (int i4 = 0; i4 < 2; i4++) {
            float4 g4 = *(const float4*)(ln_g + c0 + i4 * 4);
            float4 b4 = *(const float4*)(ln_b + c0 + i4 * 4);
            hb[i4 * 4 + 0] = f2bf((vv[i4 * 4 + 0] - mu) * rs * g4.x + b4.x);
            hb[i4 * 4 + 1] = f2bf((vv[i4 * 4 + 1] - mu) * rs * g4.y + b4.y);
            hb[i4 * 4 + 2] = f2bf((vv[i4 * 4 + 2] - mu) * rs * g4.z + b4.z);
            hb[i4 * 4 + 3] = f2bf((vv[i4 * 4 + 3] - mu) * rs * g4.w + b4.w);
        }
        *(ushort4*)&h[j * 136 + c0] = *(ushort4*)&hb[0];
        *(ushort4*)&h[j * 136 + c0 + 4] = *(ushort4*)&hb[4];
    }
    __syncthreads();

    {
        bshort8 a[4];
#pragma unroll
        for (int ks = 0; ks < 4; ks++)
            a[ks] = *(const bshort8*)(h + l15 * 136 + ks * 32 + quad * 8);
#pragma unroll
        for (int nt = 0; nt < 8; nt++) {
            int n0 = w * 128 + nt * 16;
            f32x4 acc = zero4;
#pragma unroll
            for (int ks = 0; ks < 4; ks++) {
                bshort8 bfr = *(const bshort8*)(gw1t + (size_t)(n0 + l15) * 128 + ks * 32 + quad * 8);
                acc = __builtin_amdgcn_mfma_f32_16x16x32_bf16(a[ks], bfr, acc, 0, 0, 0);
            }
            float bias = b1[n0 + l15];
#pragma unroll
            for (int r = 0; r < 4; r++)
                h1[(quad * 4 + r) * 520 + n0 + l15] = f2bf(gelu_exact(acc[r] + bias));
        }
    }
    __syncthreads();

    f32x4 acc2[2]; acc2[0] = zero4; acc2[1] = zero4;
#pragma unroll 4
    for (int ks = 0; ks < 16; ks++) {
        bshort8 a = *(const bshort8*)(h1 + l15 * 520 + ks * 32 + quad * 8);
#pragma unroll
        for (int nt = 0; nt < 2; nt++) {
            int n0 = w * 32 + nt * 16;
            bshort8 bfr = *(const bshort8*)(gw2t + (size_t)(n0 + l15) * 512 + ks * 32 + quad * 8);
            acc2[nt] = __builtin_amdgcn_mfma_f32_16x16x32_bf16(a, bfr, acc2[nt], 0, 0, 0);
        }
    }
    __syncthreads();

    {
#pragma unroll
        for (int nt = 0; nt < 2; nt++) {
            int n0 = w * 32 + nt * 16;
            float bias = b2[n0 + l15];
#pragma unroll
            for (int r = 0; r < 4; r++) {
                int m = quad * 4 + r;
                float ov = xs[m * 132 + n0 + l15] + acc2[nt][r] + bias;
                of32[m * 132 + n0 + l15] = ov;
                xg4[((size_t)(b * GN) + n0g + m) * 128 + n0 + l15] = ov;
            }
        }
    }
    __syncthreads();

    {
        int cw = t >> 1, hf = t & 1, j0 = hf * 8;
        float* dst = gout + ((size_t)(b * 128 + cw)) * GN + n0g + j0;
#pragma unroll
        for (int i4 = 0; i4 < 2; i4++) {
            float4 ov = { of32[(j0 + i4 * 4 + 0) * 132 + cw], of32[(j0 + i4 * 4 + 1) * 132 + cw],
                          of32[(j0 + i4 * 4 + 2) * 132 + cw], of32[(j0 + i4 * 4 + 3) * 132 + cw] };
            *(float4*)(dst + i4 * 4) = ov;
        }
    }
}

// ---------------- K4a: routing q/k ----------------
__global__ void k_routing_qk(const float* __restrict__ xg4,
                             const float* __restrict__ rq_w, const float* __restrict__ rq_b,
                             const float* __restrict__ rk_w, const float* __restrict__ rk_b,
                             float* __restrict__ qh, float* __restrict__ kh) {
    int wid = blockIdx.x; int b = wid / NW, n = wid % NW;
    int c = threadIdx.x;
    int i1 = n / 64, i2 = (n / 8) % 8, i3 = n % 8;
    __shared__ float g[CDIM];
    float s = 0.f;
#pragma unroll
    for (int j = 0; j < W3G; j++) {
        int ds = j >> 2, dh = (j >> 1) & 1, dw = j & 1;
        int gi = ((i1 * 2 + ds) * GH + (i2 * 2 + dh)) * GW + (i3 * 2 + dw);
        s += xg4[((size_t)(b * GN + gi)) * CDIM + c];
    }
    g[c] = s * (1.0f / W3G);
    __syncthreads();
    float aq = rq_b[c], ak = rk_b[c];
    for (int k = 0; k < CDIM; k++) { float gv = g[k]; aq = fmaf(gv, rq_w[k * CDIM + c], aq); ak = fmaf(gv, rk_w[k * CDIM + c], ak); }
    qh[(size_t)wid * CDIM + c] = aq;
    kh[(size_t)wid * CDIM + c] = ak;
}

// ---------------- K4b: top-k ----------------
__global__ void k_topk(const float* __restrict__ qh, const float* __restrict__ kh,
                       int* __restrict__ tidx) {
    int wid = blockIdx.x; int b = wid / NW;
    int m = threadIdx.x;
    __shared__ float q[CDIM];
    __shared__ float lv[NW];
    __shared__ int li[NW];
    if (m < CDIM) q[m] = qh[(size_t)wid * CDIM + m] * ROUTE_SCALE;
    __syncthreads();
    float acc = 0.f;
    const float* kr = kh + ((size_t)b * NW + m) * CDIM;
    for (int k = 0; k < CDIM; k++) acc = fmaf(q[k], kr[k], acc);
#pragma unroll
    for (int sel = 0; sel < TOPK; sel++) {
        lv[m] = acc; li[m] = m; __syncthreads();
#pragma unroll
        for (int s = 128; s > 0; s >>= 1) {
            if (m < s) {
                if (lv[m + s] > lv[m] || (lv[m + s] == lv[m] && li[m + s] < li[m])) {
                    lv[m] = lv[m + s]; li[m] = li[m + s];
                }
            }
            __syncthreads();
        }
        int best = li[0]; __syncthreads();
        if (m == best) acc = -1e30f;
        if (m == 0) tidx[wid * TOPK + sel] = best;
    }
}

// ---------------- K5a: LN local tokens -> lnsc bf16 ----------------
__global__ __launch_bounds__(256) void k_lnsc_local(const float* __restrict__ x_in,
        const float* __restrict__ ln_g, const float* __restrict__ ln_b,
        unsigned short* __restrict__ lnsc) {
    int blk = blockIdx.x;
    int wt = blk & 1; int hh = (blk >> 1) & 31; int s = (blk >> 6) & 15; int b = blk >> 10;
    int w0 = wt * 16;
    int t = threadIdx.x;
    __shared__ float tile[16][132];
    {
        int c = t >> 1; int wq = (t & 1) * 8;
        const float* src = x_in + (((size_t)(b * 128 + c) * SS + s)) * 1024 + hh * 32 + w0 + wq;
        float4 v0 = *(const float4*)src;
        float4 v1 = *(const float4*)(src + 4);
        tile[wq + 0][c] = v0.x; tile[wq + 1][c] = v0.y; tile[wq + 2][c] = v0.z; tile[wq + 3][c] = v0.w;
        tile[wq + 4][c] = v1.x; tile[wq + 5][c] = v1.y; tile[wq + 6][c] = v1.z; tile[wq + 7][c] = v1.w;
    }
    __syncthreads();
    int w = t >> 4; int j = t & 15;
    float vals[8];
    float s1 = 0.f;
#pragma unroll
    for (int i = 0; i < 8; i++) { vals[i] = tile[w][j * 8 + i]; s1 += vals[i]; }
    s1 = shfl_sum16(s1);
    float mu = s1 * (1.0f / 128.0f);
    float s2 = 0.f;
#pragma unroll
    for (int i = 0; i < 8; i++) { float d = vals[i] - mu; s2 += d * d; }
    s2 = shfl_sum16(s2);
    float rs = rsqrtf(s2 * (1.0f / 128.0f) + LN_EPS);
    float4 g0 = *(const float4*)(ln_g + j * 8);
    float4 g1 = *(const float4*)(ln_g + j * 8 + 4);
    float4 b0 = *(const float4*)(ln_b + j * 8);
    float4 b1 = *(const float4*)(ln_b + j * 8 + 4);
    float gv[8] = { g0.x, g0.y, g0.z, g0.w, g1.x, g1.y, g1.z, g1.w };
    float bv[8] = { b0.x, b0.y, b0.z, b0.w, b1.x, b1.y, b1.z, b1.w };
    int ww = w0 + w;
    int n = (s >> 2) * 64 + (hh >> 2) * 8 + (ww >> 2);
    int slot = (s & 3) * 16 + (hh & 3) * 4 + (ww & 3);
    unsigned short* dst = lnsc + ((size_t)(b * NW + n) * W3 + slot) * 128 + j * 8;
    ushort4 u0, u1;
    u0.x = f2bf((vals[0] - mu) * rs * gv[0] + bv[0]);
    u0.y = f2bf((vals[1] - mu) * rs * gv[1] + bv[1]);
    u0.z = f2bf((vals[2] - mu) * rs * gv[2] + bv[2]);
    u0.w = f2bf((vals[3] - mu) * rs * gv[3] + bv[3]);
    u1.x = f2bf((vals[4] - mu) * rs * gv[4] + bv[4]);
    u1.y = f2bf((vals[5] - mu) * rs * gv[5] + bv[5]);
    u1.z = f2bf((vals[6] - mu) * rs * gv[6] + bv[6]);
    u1.w = f2bf((vals[7] - mu) * rs * gv[7] + bv[7]);
    *(ushort4*)dst = u0;
    *(ushort4*)(dst + 4) = u1;
}

// ---------------- K5b: LN gathered global tokens -> lnsc bf16 ----------------
__global__ __launch_bounds__(256) void k_lnsc_gath(const float* __restrict__ xg4,
        const int* __restrict__ tidx,
        const float* __restrict__ ln_g, const float* __restrict__ ln_b,
        unsigned short* __restrict__ lnsc) {
    int blk = blockIdx.x;
    int kk = blk & 3; int wn = blk >> 2;
    int b = wn >> 8;
    int g = tidx[wn * TOPK + kk];
    int gi1 = g >> 6, gi2 = (g >> 3) & 7, gi3 = g & 7;
    int t = threadIdx.x; int j = t >> 5, lj = t & 31;
    int ds = j >> 2, dh = (j >> 1) & 1, dw = j & 1;
    int gi = ((gi1 * 2 + ds) * GH + (gi2 * 2 + dh)) * GW + (gi3 * 2 + dw);
    float4 v = *(const float4*)(xg4 + ((size_t)(b * GN + gi)) * 128 + lj * 4);
    float s1 = shfl_sum32(v.x + v.y + v.z + v.w);
    float mu = s1 * (1.0f / 128.0f);
    float d0 = v.x - mu, d1 = v.y - mu, d2 = v.z - mu, d3 = v.w - mu;
    float s2 = shfl_sum32(d0 * d0 + d1 * d1 + d2 * d2 + d3 * d3);
    float rs = rsqrtf(s2 * (1.0f / 128.0f) + LN_EPS);
    float4 g4 = *(const float4*)(ln_g + lj * 4);
    float4 b4 = *(const float4*)(ln_b + lj * 4);
    ushort4 u;
    u.x = f2bf(d0 * rs * g4.x + b4.x);
    u.y = f2bf(d1 * rs * g4.y + b4.y);
    u.z = f2bf(d2 * rs * g4.z + b4.z);
    u.w = f2bf(d3 * rs * g4.w + b4.w);
    *(ushort4*)(lnsc + ((size_t)wn * W3 + 64 + kk * 8 + j) * 128 + lj * 4) = u;
}

// ---------------- K6: local attention via MFMA, one window/block, X staged in LDS ----------------
// LDS: Xs[96*128] swizzled (24576) + Ks[96*128] swizzled (24576) + Vts[128*104] (26624)
//      + Ps[4][16*40] (5120) = 80896 B -> 2 blocks/CU. Q A-frags in registers.
__global__ __launch_bounds__(256) void k_local_mfma3(const unsigned short* __restrict__ lnsc,
        const unsigned short* __restrict__ wt, const float* __restrict__ gqkv_b,
        float* __restrict__ aout) {
    int wn = blockIdx.x;
    int t = threadIdx.x; int w = t >> 6; int lane = t & 63;
    int l15 = lane & 15, quad = lane >> 4;
    __shared__ __align__(16) unsigned short Xs[96 * 128];
    __shared__ __align__(16) unsigned short Ks[96 * 128];
    __shared__ __align__(16) unsigned short Vts[128 * 104];
    __shared__ __align__(16) unsigned short Ps[4][16 * 40];

    const unsigned short* Xb = lnsc + (size_t)wn * W3 * 128;
    f32x4 zero4 = {0.f, 0.f, 0.f, 0.f};
    bshort8 zfrag = {0, 0, 0, 0, 0, 0, 0, 0};
    unsigned short* Pw = &Ps[w][0];

    // ---- stage X coalesced into swizzled LDS ----
#pragma unroll
    for (int i = 0; i < 6; i++) {
        int e = t + 256 * i;          // 0..1535 chunks of 8 shorts
        int row = e >> 4, g = e & 15;
        int sg = g ^ (row & 7);
        *(bshort8*)&Xs[row * 128 + sg * 8] = *(const bshort8*)&Xb[row * 128 + g * 8];
    }
    __syncthreads();

    // ---- Q projection -> registers (wave w owns heads 2w, 2w+1) ----
    bshort8 qfrag[2][4];
#pragma unroll
    for (int hh2 = 0; hh2 < 2; hh2++) {
        int h = 2 * w + hh2;
        for (int mt = 0; mt < 4; mt++) {
            f32x4 acc = zero4;
#pragma unroll
            for (int ks = 0; ks < 4; ks++) {
                bshort8 a = lds_swz(Xs, mt * 16 + l15, ks * 4 + quad);
                bshort8 bfr = *(const bshort8*)(wt + (h * 16 + l15) * 128 + ks * 32 + quad * 8);
                acc = __builtin_amdgcn_mfma_f32_16x16x32_bf16(a, bfr, acc, 0, 0, 0);
            }
            float bias = gqkv_b[h * 16 + l15] * ROUTE_SCALE;
#pragma unroll
            for (int r = 0; r < 4; r++)
                Pw[(quad * 4 + r) * 40 + l15] = f2bf(acc[r] + bias);
            bshort8 aq = zfrag;
            if (quad < 2) aq = *(const bshort8*)(Pw + l15 * 40 + quad * 8);
            qfrag[hh2][mt] = aq;
        }
    }

    // ---- K projection -> swizzled Ks; wave w owns col tiles {w, w+4} ----
    for (int mt = 0; mt < 6; mt++) {
        bshort8 a[4];
#pragma unroll
        for (int ks = 0; ks < 4; ks++)
            a[ks] = lds_swz(Xs, mt * 16 + l15, ks * 4 + quad);
#pragma unroll
        for (int which = 0; which < 2; which++) {
            int nt8 = w + which * 4;
            int n0g = 128 + nt8 * 16;
            f32x4 acc = zero4;
#pragma unroll
            for (int ks = 0; ks < 4; ks++) {
                bshort8 bfr = *(const bshort8*)(wt + (n0g + l15) * 128 + ks * 32 + quad * 8);
                acc = __builtin_amdgcn_mfma_f32_16x16x32_bf16(a[ks], bfr, acc, 0, 0, 0);
            }
            float bias = gqkv_b[n0g + l15];
            int col = nt8 * 16 + l15;
            int gcol = col >> 3, e = col & 7;
#pragma unroll
            for (int r = 0; r < 4; r++) {
                int row = mt * 16 + quad * 4 + r;
                Ks[row * 128 + ((gcol ^ (row & 7)) << 3) + e] = f2bf(acc[r] + bias);
            }
        }
    }
    // ---- Vt projection (V transposed): wave w owns d tiles {2w, 2w+1} ----
    for (int which = 0; which < 2; which++) {
        int mtv = 2 * w + which;
        bshort8 a[4];
#pragma unroll
        for (int ks = 0; ks < 4; ks++)
            a[ks] = *(const bshort8*)(wt + (256 + mtv * 16 + l15) * 128 + ks * 32 + quad * 8);
        float biasr[4];
#pragma unroll
        for (int r = 0; r < 4; r++) biasr[r] = gqkv_b[256 + mtv * 16 + quad * 4 + r];
        for (int ntv = 0; ntv < 6; ntv++) {
            f32x4 acc = zero4;
#pragma unroll
            for (int ks = 0; ks < 4; ks++) {
                bshort8 bfr = lds_swz(Xs, ntv * 16 + l15, ks * 4 + quad);
                acc = __builtin_amdgcn_mfma_f32_16x16x32_bf16(a[ks], bfr, acc, 0, 0, 0);
            }
#pragma unroll
            for (int r = 0; r < 4; r++)
                Vts[(mtv * 16 + quad * 4 + r) * 104 + ntv * 16 + l15] = f2bf(acc[r] + biasr[r]);
        }
    }
    __syncthreads();

    // ---- attention: wave w -> heads 2w, 2w+1 ----
#pragma unroll
    for (int hh2 = 0; hh2 < 2; hh2++) {
        int h = 2 * w + hh2;
        for (int mt = 0; mt < 4; mt++) {
            bshort8 aq = qfrag[hh2][mt];
            float rsum[4] = {0.f, 0.f, 0.f, 0.f};
            f32x4 oacc = zero4;
#pragma unroll
            for (int kc = 0; kc < 96; kc += 32) {
#pragma unroll
                for (int sub = 0; sub < 2; sub++) {
                    int nt = (kc >> 4) + sub;
                    bshort8 bk = zfrag;
                    if (quad < 2) {
                        int row = nt * 16 + l15;
                        int sg = (h * 2 + quad) ^ (row & 7);
                        bk = *(const bshort8*)&Ks[row * 128 + sg * 8];
                    }
                    f32x4 s = __builtin_amdgcn_mfma_f32_16x16x32_bf16(aq, bk, zero4, 0, 0, 0);
#pragma unroll
                    for (int r = 0; r < 4; r++) {
                        float p = __expf(s[r]);
                        rsum[r] += p;
                        Pw[(quad * 4 + r) * 40 + sub * 16 + l15] = f2bf(p);
                    }
                }
                bshort8 ap = *(const bshort8*)(Pw + l15 * 40 + quad * 8);
                bshort8 bv = *(const bshort8*)(Vts + (h * 16 + l15) * 104 + kc + quad * 8);
                oacc = __builtin_amdgcn_mfma_f32_16x16x32_bf16(ap, bv, oacc, 0, 0, 0);
            }
#pragma unroll
            for (int r = 0; r < 4; r++) {
                float v = rsum[r];
                v += __shfl_xor(v, 1); v += __shfl_xor(v, 2);
                v += __shfl_xor(v, 4); v += __shfl_xor(v, 8);
                rsum[r] = v;
            }
#pragma unroll
            for (int r = 0; r < 4; r++)
                aout[((size_t)wn * W3L + mt * 16 + quad * 4 + r) * 128 + h * 16 + l15]
                    = oacc[r] / rsum[r];
        }
    }
}

// ---------------- K7: wo projection + shortcut via MFMA, 32 spatial tokens/block ----------------
__global__ __launch_bounds__(256) void k_wo_mfma(const float* __restrict__ aout,
        const unsigned short* __restrict__ wot, const float* __restrict__ wo_b,
        const float* __restrict__ x_in, float* __restrict__ lpre) {
    int blk = blockIdx.x; int T0 = blk * 32;
    int b = T0 >> 14; int sp0 = T0 & 16383;
    int t = threadIdx.x; int w = t >> 6; int lane = t & 63;
    int l15 = lane & 15, quad = lane >> 4;
    __shared__ __align__(16) unsigned short as2[32 * 136];
    __shared__ __align__(16) float xs[32 * 132];
    f32x4 zero4 = {0.f, 0.f, 0.f, 0.f};

    {
        int j = t >> 3, p = t & 7, c0 = p * 16;
        int sp = sp0 + j;
        int s = sp >> 10, hh = (sp >> 5) & 31, ww = sp & 31;
        int n = (s >> 2) * 64 + (hh >> 2) * 8 + (ww >> 2);
        int slot = (s & 3) * 16 + (hh & 3) * 4 + (ww & 3);
        const float* src = aout + (((size_t)(b * NW + n)) * W3L + slot) * 128 + c0;
#pragma unroll
        for (int i4 = 0; i4 < 4; i4++) {
            float4 v = *(const float4*)(src + i4 * 4);
            ushort4 u = { f2bf(v.x), f2bf(v.y), f2bf(v.z), f2bf(v.w) };
            *(ushort4*)&as2[j * 136 + c0 + i4 * 4] = u;
        }
    }
    {
        int c = t >> 1, half = t & 1, j0 = half * 16;
        const float* src = x_in + ((size_t)(b * 128 + c)) * 16384 + sp0 + j0;
#pragma unroll
        for (int i4 = 0; i4 < 4; i4++) {
            float4 v = *(const float4*)(src + i4 * 4);
            xs[(j0 + i4 * 4 + 0) * 132 + c] = v.x;
            xs[(j0 + i4 * 4 + 1) * 132 + c] = v.y;
            xs[(j0 + i4 * 4 + 2) * 132 + c] = v.z;
            xs[(j0 + i4 * 4 + 3) * 132 + c] = v.w;
        }
    }
    __syncthreads();

    bshort8 a[2][4];
#pragma unroll
    for (int mt = 0; mt < 2; mt++)
#pragma unroll
        for (int ks = 0; ks < 4; ks++)
            a[mt][ks] = *(const bshort8*)(as2 + (mt * 16 + l15) * 136 + ks * 32 + quad * 8);
#pragma unroll
    for (int nt = 0; nt < 2; nt++) {
        int n0 = w * 32 + nt * 16;
        f32x4 acc0 = zero4, acc1 = zero4;
#pragma unroll
        for (int ks = 0; ks < 4; ks++) {
            bshort8 bfr = *(const bshort8*)(wot + (n0 + l15) * 128 + ks * 32 + quad * 8);
            acc0 = __builtin_amdgcn_mfma_f32_16x16x32_bf16(a[0][ks], bfr, acc0, 0, 0, 0);
            acc1 = __builtin_amdgcn_mfma_f32_16x16x32_bf16(a[1][ks], bfr, acc1, 0, 0, 0);
        }
        float bias = wo_b[n0 + l15];
#pragma unroll
        for (int r = 0; r < 4; r++) {
            int m0 = quad * 4 + r;
            int m1 = 16 + quad * 4 + r;
            lpre[((size_t)T0 + m0) * 128 + n0 + l15] = acc0[r] + bias + xs[m0 * 132 + n0 + l15];
            lpre[((size_t)T0 + m1) * 128 + n0 + l15] = acc1[r] + bias + xs[m1 * 132 + n0 + l15];
        }
    }
}

// ---------------- K8: LN + MLP2 via MFMA, 32 tokens/block, single aliased LDS buffer ----------------
__global__ __launch_bounds__(256) void k_mlp2_mfma(const float* __restrict__ lpre,
        const float* __restrict__ ln_g, const float* __restrict__ ln_b,
        const unsigned short* __restrict__ w1t, const float* __restrict__ b1,
        const unsigned short* __restrict__ w2t, const float* __restrict__ b2,
        float* __restrict__ lout) {
    int blk = blockIdx.x;
    int T0 = blk * 32;
    int b = T0 >> 14;
    int sp = T0 & 16383;
    int t = threadIdx.x; int w = t >> 6; int lane = t & 63;
    int l15 = lane & 15, quad = lane >> 4;
    __shared__ __align__(16) unsigned short buf[32 * 520];
    float* of32 = (float*)buf;

    {
        int j = t >> 3, p = t & 7, c0 = p * 16;
        const float* src = lpre + ((size_t)T0 + j) * 128 + c0;
        float4 v0 = *(const float4*)(src + 0);
        float4 v1 = *(const float4*)(src + 4);
        float4 v2 = *(const float4*)(src + 8);
        float4 v3 = *(const float4*)(src + 12);
        float s1 = (v0.x + v0.y + v0.z + v0.w) + (v1.x + v1.y + v1.z + v1.w)
                 + (v2.x + v2.y + v2.z + v2.w) + (v3.x + v3.y + v3.z + v3.w);
        s1 = shfl_sum8(s1);
        float mu = s1 * (1.0f / 128.0f);
        float vv[16] = { v0.x, v0.y, v0.z, v0.w, v1.x, v1.y, v1.z, v1.w,
                         v2.x, v2.y, v2.z, v2.w, v3.x, v3.y, v3.z, v3.w };
        float s2 = 0.f;
#pragma unroll
        for (int i = 0; i < 16; i++) { float d = vv[i] - mu; s2 += d * d; }
        s2 = shfl_sum8(s2);
        float rs = rsqrtf(s2 * (1.0f / 128.0f) + LN_EPS);
        unsigned short hb[16];
#pragma unroll
        for (int i4 = 0; i4 < 4; i4++) {
            float4 g4 = *(const float4*)(ln_g + c0 + i4 * 4);
            float4 b4 = *(const float4*)(ln_b + c0 + i4 * 4);
            hb[i4 * 4 + 0] = f2bf((vv[i4 * 4 + 0] - mu) * rs * g4.x + b4.x);
            hb[i4 * 4 + 1] = f2bf((vv[i4 * 4 + 1] - mu) * rs * g4.y + b4.y);
            hb[i4 * 4 + 2] = f2bf((vv[i4 * 4 + 2] - mu) * rs * g4.z + b4.z);
            hb[i4 * 4 + 3] = f2bf((vv[i4 * 4 + 3] - mu) * rs * g4.w + b4.w);
        }
        *(ushort4*)&buf[j * 136 + c0 + 0] = *(ushort4*)&hb[0];
        *(ushort4*)&buf[j * 136 + c0 + 4] = *(ushort4*)&hb[4];
        *(ushort4*)&buf[j * 136 + c0 + 8] = *(ushort4*)&hb[8];
        *(ushort4*)&buf[j * 136 + c0 + 12] = *(ushort4*)&hb[12];
    }
    __syncthreads();

    bshort8 a1[2][4];
#pragma unroll
    for (int mt = 0; mt < 2; mt++)
#pragma unroll
        for (int ks = 0; ks < 4; ks++)
            a1[mt][ks] = *(const bshort8*)(buf + (mt * 16 + l15) * 136 + ks * 32 + quad * 8);
    __syncthreads();

    f32x4 zero4 = {0.f, 0.f, 0.f, 0.f};
    {
        int n0w = w * 128;
#pragma unroll
        for (int nt = 0; nt < 8; nt++) {
            int n0 = n0w + nt * 16;
            f32x4 acc0 = zero4, acc1 = zero4;
#pragma unroll
            for (int ks = 0; ks < 4; ks++) {
                bshort8 bfr = *(const bshort8*)(w1t + (size_t)(n0 + l15) * 128 + ks * 32 + quad * 8);
                acc0 = __builtin_amdgcn_mfma_f32_16x16x32_bf16(a1[0][ks], bfr, acc0, 0, 0, 0);
                acc1 = __builtin_amdgcn_mfma_f32_16x16x32_bf16(a1[1][ks], bfr, acc1, 0, 0, 0);
            }
            float bias = b1[n0 + l15];
#pragma unroll
            for (int r = 0; r < 4; r++) {
                buf[(quad * 4 + r) * 520 + n0 + l15] = f2bf(gelu_exact(acc0[r] + bias));
                buf[(16 + quad * 4 + r) * 520 + n0 + l15] = f2bf(gelu_exact(acc1[r] + bias));
            }
        }
    }
    __syncthreads();

    f32x4 acc[2][2];
    acc[0][0] = zero4; acc[0][1] = zero4; acc[1][0] = zero4; acc[1][1] = zero4;
    {
#pragma unroll 4
        for (int ks = 0; ks < 16; ks++) {
            bshort8 a0 = *(const bshort8*)(buf + (l15) * 520 + ks * 32 + quad * 8);
            bshort8 a1b = *(const bshort8*)(buf + (16 + l15) * 520 + ks * 32 + quad * 8);
#pragma unroll
            for (int nt = 0; nt < 2; nt++) {
                int n0 = w * 32 + nt * 16;
                bshort8 bfr = *(const bshort8*)(w2t + (size_t)(n0 + l15) * 512 + ks * 32 + quad * 8);
                acc[0][nt] = __builtin_amdgcn_mfma_f32_16x16x32_bf16(a0, bfr, acc[0][nt], 0, 0, 0);
                acc[1][nt] = __builtin_amdgcn_mfma_f32_16x16x32_bf16(a1b, bfr, acc[1][nt], 0, 0, 0);
            }
        }
    }
    __syncthreads();

#pragma unroll
    for (int mt = 0; mt < 2; mt++) {
#pragma unroll
        for (int nt = 0; nt < 2; nt++) {
            int n0 = w * 32 + nt * 16;
            float bias = b2[n0 + l15];
#pragma unroll
            for (int r = 0; r < 4; r++) {
                int m = mt * 16 + quad * 4 + r;
                float res = lpre[((size_t)T0 + m) * 128 + n0 + l15];
                of32[m * 132 + n0 + l15] = res + acc[mt][nt][r] + bias;
            }
        }
    }
    __syncthreads();

    {
        int c = t >> 1, half = t & 1, j0 = half * 16;
        float* dst = lout + ((size_t)(b * 128 + c)) * NSP + sp + j0;
#pragma unroll
        for (int i4 = 0; i4 < 4; i4++) {
            float4 ov = { of32[(j0 + i4 * 4 + 0) * 132 + c], of32[(j0 + i4 * 4 + 1) * 132 + c],
                          of32[(j0 + i4 * 4 + 2) * 132 + c], of32[(j0 + i4 * 4 + 3) * 132 + c] };
            *(float4*)(dst + i4 * 4) = ov;
        }
    }
}

extern "C" void kernel_launch(void* const* d_in, const int* in_sizes, int n_in,
                              void* d_out, int out_size, void* d_ws, size_t ws_size,
                              hipStream_t stream) {
    const float* x_in   = (const float*)d_in[0];
    const float* xg_in  = (const float*)d_in[1];
    const float* qkv_w  = (const float*)d_in[2];
    const float* qkv_b  = (const float*)d_in[3];
    const float* proj_w = (const float*)d_in[4];
    const float* proj_b = (const float*)d_in[5];
    const float* ln_g   = (const float*)d_in[6];
    const float* ln_b   = (const float*)d_in[7];
    const float* mlp_w1 = (const float*)d_in[8];
    const float* mlp_b1 = (const float*)d_in[9];
    const float* mlp_w2 = (const float*)d_in[10];
    const float* mlp_b2 = (const float*)d_in[11];
    const float* rq_w   = (const float*)d_in[12];
    const float* rq_b   = (const float*)d_in[13];
    const float* rk_w   = (const float*)d_in[14];
    const float* rk_b   = (const float*)d_in[15];
    const float* gqkv_w = (const float*)d_in[16];
    const float* gqkv_b = (const float*)d_in[17];
    const float* wo_w   = (const float*)d_in[18];
    const float* wo_b   = (const float*)d_in[19];
    const float* m2_w1  = (const float*)d_in[20];
    const float* m2_b1  = (const float*)d_in[21];
    const float* m2_w2  = (const float*)d_in[22];
    const float* m2_b2  = (const float*)d_in[23];

    float* out = (float*)d_out;
    float* ws  = (float*)d_ws;

    float* xg4 = ws;                                         // 524288
    float* xg  = ws + 524288;                                // 524288
    unsigned short* qgb  = (unsigned short*)(ws + 1048576);  // 524288 bf16
    unsigned short* kgb  = (unsigned short*)(ws + 1310720);  // 524288 bf16
    unsigned short* vgtb = (unsigned short*)(ws + 1572864);  // 524288 bf16 (V^T)
    float* og  = ws + 1835008;                               // 524288
    float* qh  = ws + 2359296;                               // 65536
    float* kh  = ws + 2424832;                               // 65536
    int*   tidx = (int*)(ws + 2490368);                      // 2048
    unsigned short* lnsc = (unsigned short*)(ws + 2492416);  // 6291456 bf16
    float* aout = ws + 2492416 + 3145728;                    // 4194304
    float* lpre = ws + 9832448;                              // 4194304
    unsigned short* wt   = (unsigned short*)(ws + 14026752); // 49152 bf16
    unsigned short* w1t  = (unsigned short*)(ws + 14051328); // 65536 bf16
    unsigned short* w2t  = (unsigned short*)(ws + 14084096); // 65536 bf16
    unsigned short* projt = (unsigned short*)(ws + 14116864); // 16384 bf16
    unsigned short* gw1t  = (unsigned short*)(ws + 14125056); // 65536 bf16
    unsigned short* gw2t  = (unsigned short*)(ws + 14157824); // 65536 bf16
    unsigned short* wot   = (unsigned short*)(ws + 14190592); // 16384 bf16

    const size_t L_OUT = (size_t)BATCH * CDIM * NSP;
    float* gout = out + L_OUT;

    hipLaunchKernelGGL(k_wprep_all, dim3(1344), dim3(256), 0, stream,
                       gqkv_w, m2_w1, m2_w2, proj_w, mlp_w1, mlp_w2, wo_w,
                       wt, w1t, w2t, projt, gw1t, gw2t, wot);
    hipLaunchKernelGGL(k_gqkv2, dim3(512), dim3(256), 0, stream,
                       xg_in, qkv_w, qkv_b, ln_g, ln_b, xg, qgb, kgb, vgtb);
    hipLaunchKernelGGL(k_gattn_mfma, dim3(2048), dim3(256), 0, stream, qgb, kgb, vgtb, og);
    hipLaunchKernelGGL(k_gmlp_mfma, dim3(256), dim3(256), 0, stream,
                       og, xg, projt, proj_b, ln_g, ln_b, gw1t, mlp_b1, gw2t, mlp_b2,
                       xg4, gout);
    hipLaunchKernelGGL(k_routing_qk, dim3(512), dim3(128), 0, stream,
                       xg4, rq_w, rq_b, rk_w, rk_b, qh, kh);
    hipLaunchKernelGGL(k_topk, dim3(512), dim3(256), 0, stream, qh, kh, tidx);
    hipLaunchKernelGGL(k_lnsc_local, dim3(2048), dim3(256), 0, stream,
                       x_in, ln_g, ln_b, lnsc);
    hipLaunchKernelGGL(k_lnsc_gath, dim3(2048), dim3(256), 0, stream,
                       xg4, tidx, ln_g, ln_b, lnsc);
    hipLaunchKernelGGL(k_local_mfma3, dim3(512), dim3(256), 0, stream,
                       lnsc, wt, gqkv_b, aout);
    hipLaunchKernelGGL(k_wo_mfma, dim3(1024), dim3(256), 0, stream,
                       aout, wot, wo_b, x_in, lpre);
    hipLaunchKernelGGL(k_mlp2_mfma, dim3(1024), dim3(256), 0, stream,
                       lpre, ln_g, ln_b, w1t, m2_b1, w2t, m2_b2, out);
}

// Round 10
// 288.659 us; speedup vs baseline: 1.2774x; 1.2774x over previous
//
#include <hip/hip_runtime.h>
#include <hip/hip_bf16.h>
#include <math.h>

#define BATCH 2
#define CDIM 128
#define SS 16
#define HH_ 32
#define WW_ 32
#define NSP (SS*HH_*WW_)
#define GS 8
#define GH 16
#define GW 16
#define GN (GS*GH*GW)
#define HEADS 8
#define DH 16
#define NW 256
#define W3L 64
#define W3G 8
#define TOPK 4
#define W3 (W3L + TOPK*W3G)
#define LN_EPS 1e-6f
#define ROUTE_SCALE 0.08838834764831845f
#define GATTN_SCALE 0.25f

typedef short bshort8 __attribute__((ext_vector_type(8)));
typedef float f32x4 __attribute__((ext_vector_type(4)));

__device__ __forceinline__ unsigned short f2bf(float f) {
    unsigned int u = __float_as_uint(f);
    unsigned int r = (u + 0x7fffu + ((u >> 16) & 1u)) >> 16;
    return (unsigned short)r;
}
__device__ __forceinline__ float gelu_exact(float x) {
    return 0.5f * x * (1.0f + erff(x * 0.70710678118654752f));
}
__device__ __forceinline__ float shfl_sum32(float v) {
#pragma unroll
    for (int m = 16; m > 0; m >>= 1) v += __shfl_xor(v, m);
    return v;
}
__device__ __forceinline__ float shfl_sum16(float v) {
#pragma unroll
    for (int m = 8; m > 0; m >>= 1) v += __shfl_xor(v, m);
    return v;
}
__device__ __forceinline__ float shfl_sum8(float v) {
#pragma unroll
    for (int m = 4; m > 0; m >>= 1) v += __shfl_xor(v, m);
    return v;
}

// ---------------- K0: ALL weight prep in one kernel ----------------
// wt: gqkv_w^T (ROUTE_SCALE folded into q cols) | w1t/w2t: mlp2 | projt/gw1t/gw2t: global | wot: wo
// qkvt: qkv_w[128][384] -> [384][128] bf16, GATTN_SCALE folded into q cols (n<128)
__global__ __launch_bounds__(256) void k_wprep_all(const float* __restrict__ gqkv_w,
        const float* __restrict__ m2_w1, const float* __restrict__ m2_w2,
        const float* __restrict__ proj_w, const float* __restrict__ mlp_w1,
        const float* __restrict__ mlp_w2, const float* __restrict__ wo_w,
        const float* __restrict__ qkv_w,
        unsigned short* __restrict__ wt, unsigned short* __restrict__ w1t,
        unsigned short* __restrict__ w2t, unsigned short* __restrict__ projt,
        unsigned short* __restrict__ gw1t, unsigned short* __restrict__ gw2t,
        unsigned short* __restrict__ wot, unsigned short* __restrict__ qkvt) {
    int id = blockIdx.x * 256 + threadIdx.x;   // 0..393215
    if (id < 49152) {
        int n = id >> 7, k = id & 127;
        float v = gqkv_w[k * 384 + n];
        if (n < 128) v *= ROUTE_SCALE;
        wt[id] = f2bf(v);
    } else if (id < 114688) {
        int i = id - 49152; int n = i >> 7, k = i & 127;
        w1t[i] = f2bf(m2_w1[k * 512 + n]);
    } else if (id < 180224) {
        int i = id - 114688; int n = i >> 9, k = i & 511;
        w2t[i] = f2bf(m2_w2[k * 128 + n]);
    } else if (id < 196608) {
        int i = id - 180224; int n = i >> 7, k = i & 127;
        projt[i] = f2bf(proj_w[k * 128 + n]);
    } else if (id < 262144) {
        int i = id - 196608; int n = i >> 7, k = i & 127;
        gw1t[i] = f2bf(mlp_w1[k * 512 + n]);
    } else if (id < 327680) {
        int i = id - 262144; int n = i >> 9, k = i & 511;
        gw2t[i] = f2bf(mlp_w2[k * 128 + n]);
    } else if (id < 344064) {
        int i = id - 327680; int n = i >> 7, k = i & 127;
        wot[i] = f2bf(wo_w[k * 128 + n]);
    } else {
        int i = id - 344064; int n = i >> 7, k = i & 127;
        float v = qkv_w[k * 384 + n];
        if (n < 128) v *= GATTN_SCALE;
        qkvt[i] = f2bf(v);
    }
}

// ---------------- K1: global branch qkv via MFMA, 16 tokens/block (256 blocks) ----------------
// LDS: xs[16*132] f32 (8448) + h[16*136] bf16 (4352) = 12800 B
__global__ __launch_bounds__(256) void k_gqkv_mfma(const float* __restrict__ xg_in,
        const unsigned short* __restrict__ qkvt, const float* __restrict__ qkv_b,
        const float* __restrict__ ln_g, const float* __restrict__ ln_b,
        float* __restrict__ xg, unsigned short* __restrict__ qgb,
        unsigned short* __restrict__ kgb, unsigned short* __restrict__ vgtb) {
    int blk = blockIdx.x; int b = blk >> 7; int n0 = (blk & 127) * 16;
    int t = threadIdx.x; int w = t >> 6; int lane = t & 63;
    int l15 = lane & 15, quad = lane >> 4;
    __shared__ __align__(16) float xs[16 * 132];
    __shared__ __align__(16) unsigned short h[16 * 136];
    f32x4 zero4 = {0.f, 0.f, 0.f, 0.f};

    {   // transpose load: thread t -> channel c, token-octet
        int c = t >> 1, j0 = (t & 1) * 8;
        const float* src = xg_in + ((size_t)(b * 128 + c)) * GN + n0 + j0;
        float4 v0 = *(const float4*)src;
        float4 v1 = *(const float4*)(src + 4);
        xs[(j0 + 0) * 132 + c] = v0.x; xs[(j0 + 1) * 132 + c] = v0.y;
        xs[(j0 + 2) * 132 + c] = v0.z; xs[(j0 + 3) * 132 + c] = v0.w;
        xs[(j0 + 4) * 132 + c] = v1.x; xs[(j0 + 5) * 132 + c] = v1.y;
        xs[(j0 + 6) * 132 + c] = v1.z; xs[(j0 + 7) * 132 + c] = v1.w;
    }
    __syncthreads();
    {   // LN: 16 threads/token, 8 ch each; write xg fp32 + h bf16
        int j = t >> 4, p = t & 15, c0 = p * 8;
        float vv[8]; float s1 = 0.f;
#pragma unroll
        for (int i = 0; i < 8; i++) { vv[i] = xs[j * 132 + c0 + i]; s1 += vv[i]; }
        s1 = shfl_sum16(s1);
        float mu = s1 * (1.0f / 128.0f);
        float s2 = 0.f;
#pragma unroll
        for (int i = 0; i < 8; i++) { float d = vv[i] - mu; s2 += d * d; }
        s2 = shfl_sum16(s2);
        float rs = rsqrtf(s2 * (1.0f / 128.0f) + LN_EPS);
        float* dst = xg + ((size_t)(b * GN) + n0 + j) * 128 + c0;
        *(float4*)dst = *(float4*)&vv[0];
        *(float4*)(dst + 4) = *(float4*)&vv[4];
        unsigned short hb[8];
#pragma unroll
        for (int i4 = 0; i4 < 2; i4++) {
            float4 g4 = *(const float4*)(ln_g + c0 + i4 * 4);
            float4 b4 = *(const float4*)(ln_b + c0 + i4 * 4);
            hb[i4 * 4 + 0] = f2bf((vv[i4 * 4 + 0] - mu) * rs * g4.x + b4.x);
            hb[i4 * 4 + 1] = f2bf((vv[i4 * 4 + 1] - mu) * rs * g4.y + b4.y);
            hb[i4 * 4 + 2] = f2bf((vv[i4 * 4 + 2] - mu) * rs * g4.z + b4.z);
            hb[i4 * 4 + 3] = f2bf((vv[i4 * 4 + 3] - mu) * rs * g4.w + b4.w);
        }
        *(ushort4*)&h[j * 136 + c0] = *(ushort4*)&hb[0];
        *(ushort4*)&h[j * 136 + c0 + 4] = *(ushort4*)&hb[4];
    }
    __syncthreads();

    bshort8 a[4];
#pragma unroll
    for (int ks = 0; ks < 4; ks++)
        a[ks] = *(const bshort8*)(h + l15 * 136 + ks * 32 + quad * 8);
    int bh_base = b * HEADS;
    // q and k tiles: wave w owns heads {2w, 2w+1} for each
#pragma unroll
    for (int part = 0; part < 2; part++) {
#pragma unroll
        for (int which = 0; which < 2; which++) {
            int nt = 2 * w + which;
            int ncol = part * 128 + nt * 16;
            f32x4 acc = zero4;
#pragma unroll
            for (int ks = 0; ks < 4; ks++) {
                bshort8 bfr = *(const bshort8*)(qkvt + (size_t)(ncol + l15) * 128 + ks * 32 + quad * 8);
                acc = __builtin_amdgcn_mfma_f32_16x16x32_bf16(a[ks], bfr, acc, 0, 0, 0);
            }
            float bias = qkv_b[ncol + l15] * (part == 0 ? GATTN_SCALE : 1.f);
            unsigned short* dst = (part == 0) ? qgb : kgb;
#pragma unroll
            for (int r = 0; r < 4; r++)
                dst[((size_t)(bh_base + nt) * GN + n0 + quad * 4 + r) * DH + l15] = f2bf(acc[r] + bias);
        }
    }
    // v tiles transposed: wave w owns heads {2w, 2w+1}; A = Wv^T rows, B = token rows
#pragma unroll
    for (int which = 0; which < 2; which++) {
        int mtv = 2 * w + which;
        f32x4 acc = zero4;
#pragma unroll
        for (int ks = 0; ks < 4; ks++) {
            bshort8 aw = *(const bshort8*)(qkvt + (size_t)(256 + mtv * 16 + l15) * 128 + ks * 32 + quad * 8);
            acc = __builtin_amdgcn_mfma_f32_16x16x32_bf16(aw, a[ks], acc, 0, 0, 0);
        }
#pragma unroll
        for (int r = 0; r < 4; r++) {
            float bias = qkv_b[256 + mtv * 16 + quad * 4 + r];
            vgtb[((size_t)(bh_base + mtv) * DH + quad * 4 + r) * GN + n0 + l15] = f2bf(acc[r] + bias);
        }
    }
}

// ---------------- K2: global attention via MFMA bf16 ----------------
__global__ __launch_bounds__(256) void k_gattn_mfma(const unsigned short* __restrict__ qgb,
        const unsigned short* __restrict__ kgb, const unsigned short* __restrict__ vgtb,
        float* __restrict__ og) {
    int blk = blockIdx.x;
    int bh = blk >> 7; int qt = (blk & 127) << 4;
    int b = bh >> 3, hh = bh & 7;
    int t = threadIdx.x; int w = t >> 6; int lane = t & 63;
    int col = lane & 15, quad = lane >> 4;
    __shared__ __align__(16) unsigned short Pbuf[4 * 16 * 40];
    __shared__ float po[4][64][4];
    __shared__ float pl[4][64][4];

    bshort8 aq = {0, 0, 0, 0, 0, 0, 0, 0};
    if (quad < 2)
        aq = *(const bshort8*)(qgb + ((size_t)bh * GN + qt + col) * DH + quad * 8);

    f32x4 o = {0.f, 0.f, 0.f, 0.f};
    float lsum[4] = {0.f, 0.f, 0.f, 0.f};
    const unsigned short* kb = kgb + (size_t)bh * GN * DH;
    const unsigned short* vb = vgtb + (size_t)bh * DH * GN;
    unsigned short* pb = Pbuf + w * (16 * 40);
    int row0 = quad * 4;
    int kbeg = w * 512;
    for (int kc = kbeg; kc < kbeg + 512; kc += 32) {
        bshort8 bk0 = {0, 0, 0, 0, 0, 0, 0, 0};
        bshort8 bk1 = {0, 0, 0, 0, 0, 0, 0, 0};
        if (quad < 2) {
            bk0 = *(const bshort8*)(kb + (size_t)(kc + col) * DH + quad * 8);
            bk1 = *(const bshort8*)(kb + (size_t)(kc + 16 + col) * DH + quad * 8);
        }
        f32x4 z = {0.f, 0.f, 0.f, 0.f};
        f32x4 s0 = __builtin_amdgcn_mfma_f32_16x16x32_bf16(aq, bk0, z, 0, 0, 0);
        f32x4 s1 = __builtin_amdgcn_mfma_f32_16x16x32_bf16(aq, bk1, z, 0, 0, 0);
        float p0[4], p1[4];
#pragma unroll
        for (int r = 0; r < 4; r++) {
            p0[r] = __expf(s0[r]); p1[r] = __expf(s1[r]);
            lsum[r] += p0[r] + p1[r];
        }
#pragma unroll
        for (int r = 0; r < 4; r++) {
            pb[(row0 + r) * 40 + col] = f2bf(p0[r]);
            pb[(row0 + r) * 40 + 16 + col] = f2bf(p1[r]);
        }
        bshort8 pA = *(const bshort8*)(pb + col * 40 + quad * 8);
        bshort8 bv = *(const bshort8*)(vb + (size_t)col * GN + kc + quad * 8);
        o = __builtin_amdgcn_mfma_f32_16x16x32_bf16(pA, bv, o, 0, 0, 0);
    }
#pragma unroll
    for (int r = 0; r < 4; r++) {
        float v = lsum[r];
        v += __shfl_xor(v, 1); v += __shfl_xor(v, 2);
        v += __shfl_xor(v, 4); v += __shfl_xor(v, 8);
        lsum[r] = v;
    }
#pragma unroll
    for (int r = 0; r < 4; r++) { po[w][lane][r] = o[r]; pl[w][lane][r] = lsum[r]; }
    __syncthreads();
    if (w == 0) {
#pragma unroll
        for (int r = 0; r < 4; r++) {
            float os = po[0][lane][r] + po[1][lane][r] + po[2][lane][r] + po[3][lane][r];
            float ls = pl[0][lane][r] + pl[1][lane][r] + pl[2][lane][r] + pl[3][lane][r];
            og[((size_t)(b * GN) + qt + quad * 4 + r) * 128 + hh * 16 + col] = os / ls;
        }
    }
}

// ---------------- K3: global proj+residual+LN+MLP via MFMA, 16 tokens/block ----------------
__global__ __launch_bounds__(256) void k_gmlp_mfma(const float* __restrict__ og,
        const float* __restrict__ xg,
        const unsigned short* __restrict__ projt, const float* __restrict__ proj_b,
        const float* __restrict__ ln_g, const float* __restrict__ ln_b,
        const unsigned short* __restrict__ gw1t, const float* __restrict__ b1,
        const unsigned short* __restrict__ gw2t, const float* __restrict__ b2,
        float* __restrict__ xg4, float* __restrict__ gout) {
    int blk = blockIdx.x; int b = blk >> 7; int n0g = (blk & 127) * 16;
    int t = threadIdx.x; int w = t >> 6; int lane = t & 63;
    int l15 = lane & 15, quad = lane >> 4;
    __shared__ __align__(16) unsigned short ao[16 * 136];
    __shared__ __align__(16) float xs[16 * 132];
    __shared__ __align__(16) unsigned short h[16 * 136];
    __shared__ __align__(16) unsigned short h1[16 * 520];
    float* of32 = (float*)h1;
    f32x4 zero4 = {0.f, 0.f, 0.f, 0.f};

    {
        int j = t >> 4, p = t & 15, c0 = p * 8;
        size_t base = ((size_t)(b * GN) + n0g + j) * 128 + c0;
        float4 v0 = *(const float4*)(og + base);
        float4 v1 = *(const float4*)(og + base + 4);
        ushort4 u0 = { f2bf(v0.x), f2bf(v0.y), f2bf(v0.z), f2bf(v0.w) };
        ushort4 u1 = { f2bf(v1.x), f2bf(v1.y), f2bf(v1.z), f2bf(v1.w) };
        *(ushort4*)&ao[j * 136 + c0] = u0;
        *(ushort4*)&ao[j * 136 + c0 + 4] = u1;
        *(float4*)&xs[j * 132 + c0] = *(const float4*)(xg + base);
        *(float4*)&xs[j * 132 + c0 + 4] = *(const float4*)(xg + base + 4);
    }
    __syncthreads();

    {
        bshort8 a[4];
#pragma unroll
        for (int ks = 0; ks < 4; ks++)
            a[ks] = *(const bshort8*)(ao + l15 * 136 + ks * 32 + quad * 8);
#pragma unroll
        for (int nt = 0; nt < 2; nt++) {
            int n0 = w * 32 + nt * 16;
            f32x4 acc = zero4;
#pragma unroll
            for (int ks = 0; ks < 4; ks++) {
                bshort8 bfr = *(const bshort8*)(projt + (n0 + l15) * 128 + ks * 32 + quad * 8);
                acc = __builtin_amdgcn_mfma_f32_16x16x32_bf16(a[ks], bfr, acc, 0, 0, 0);
            }
            float bias = proj_b[n0 + l15];
#pragma unroll
            for (int r = 0; r < 4; r++) {
                int m = quad * 4 + r;
                xs[m * 132 + n0 + l15] += acc[r] + bias;
            }
        }
    }
    __syncthreads();

    {
        int j = t >> 4, p = t & 15, c0 = p * 8;
        float vv[8]; float s1 = 0.f;
#pragma unroll
        for (int i = 0; i < 8; i++) { vv[i] = xs[j * 132 + c0 + i]; s1 += vv[i]; }
        s1 = shfl_sum16(s1);
        float mu = s1 * (1.0f / 128.0f);
        float s2 = 0.f;
#pragma unroll
        for (int i = 0; i < 8; i++) { float d = vv[i] - mu; s2 += d * d; }
        s2 = shfl_sum16(s2);
        float rs = rsqrtf(s2 * (1.0f / 128.0f) + LN_EPS);
        unsigned short hb[8];
#pragma unroll
        for (int i4 = 0; i4 < 2; i4++) {
            float4 g4 = *(const float4*)(ln_g + c0 + i4 * 4);
            float4 b4 = *(const float4*)(ln_b + c0 + i4 * 4);
            hb[i4 * 4 + 0] = f2bf((vv[i4 * 4 + 0] - mu) * rs * g4.x + b4.x);
            hb[i4 * 4 + 1] = f2bf((vv[i4 * 4 + 1] - mu) * rs * g4.y + b4.y);
            hb[i4 * 4 + 2] = f2bf((vv[i4 * 4 + 2] - mu) * rs * g4.z + b4.z);
            hb[i4 * 4 + 3] = f2bf((vv[i4 * 4 + 3] - mu) * rs * g4.w + b4.w);
        }
        *(ushort4*)&h[j * 136 + c0] = *(ushort4*)&hb[0];
        *(ushort4*)&h[j * 136 + c0 + 4] = *(ushort4*)&hb[4];
    }
    __syncthreads();

    {
        bshort8 a[4];
#pragma unroll
        for (int ks = 0; ks < 4; ks++)
            a[ks] = *(const bshort8*)(h + l15 * 136 + ks * 32 + quad * 8);
#pragma unroll
        for (int nt = 0; nt < 8; nt++) {
            int n0 = w * 128 + nt * 16;
            f32x4 acc = zero4;
#pragma unroll
            for (int ks = 0; ks < 4; ks++) {
                bshort8 bfr = *(const bshort8*)(gw1t + (size_t)(n0 + l15) * 128 + ks * 32 + quad * 8);
                acc = __builtin_amdgcn_mfma_f32_16x16x32_bf16(a[ks], bfr, acc, 0, 0, 0);
            }
            float bias = b1[n0 + l15];
#pragma unroll
            for (int r = 0; r < 4; r++)
                h1[(quad * 4 + r) * 520 + n0 + l15] = f2bf(gelu_exact(acc[r] + bias));
        }
    }
    __syncthreads();

    f32x4 acc2[2]; acc2[0] = zero4; acc2[1] = zero4;
#pragma unroll 4
    for (int ks = 0; ks < 16; ks++) {
        bshort8 a = *(const bshort8*)(h1 + l15 * 520 + ks * 32 + quad * 8);
#pragma unroll
        for (int nt = 0; nt < 2; nt++) {
            int n0 = w * 32 + nt * 16;
            bshort8 bfr = *(const bshort8*)(gw2t + (size_t)(n0 + l15) * 512 + ks * 32 + quad * 8);
            acc2[nt] = __builtin_amdgcn_mfma_f32_16x16x32_bf16(a, bfr, acc2[nt], 0, 0, 0);
        }
    }
    __syncthreads();

    {
#pragma unroll
        for (int nt = 0; nt < 2; nt++) {
            int n0 = w * 32 + nt * 16;
            float bias = b2[n0 + l15];
#pragma unroll
            for (int r = 0; r < 4; r++) {
                int m = quad * 4 + r;
                float ov = xs[m * 132 + n0 + l15] + acc2[nt][r] + bias;
                of32[m * 132 + n0 + l15] = ov;
                xg4[((size_t)(b * GN) + n0g + m) * 128 + n0 + l15] = ov;
            }
        }
    }
    __syncthreads();

    {
        int cw = t >> 1, hf = t & 1, j0 = hf * 8;
        float* dst = gout + ((size_t)(b * 128 + cw)) * GN + n0g + j0;
#pragma unroll
        for (int i4 = 0; i4 < 2; i4++) {
            float4 ov = { of32[(j0 + i4 * 4 + 0) * 132 + cw], of32[(j0 + i4 * 4 + 1) * 132 + cw],
                          of32[(j0 + i4 * 4 + 2) * 132 + cw], of32[(j0 + i4 * 4 + 3) * 132 + cw] };
            *(float4*)(dst + i4 * 4) = ov;
        }
    }
}

// ---------------- K4a: routing q/k ----------------
__global__ void k_routing_qk(const float* __restrict__ xg4,
                             const float* __restrict__ rq_w, const float* __restrict__ rq_b,
                             const float* __restrict__ rk_w, const float* __restrict__ rk_b,
                             float* __restrict__ qh, float* __restrict__ kh) {
    int wid = blockIdx.x; int b = wid / NW, n = wid % NW;
    int c = threadIdx.x;
    int i1 = n / 64, i2 = (n / 8) % 8, i3 = n % 8;
    __shared__ float g[CDIM];
    float s = 0.f;
#pragma unroll
    for (int j = 0; j < W3G; j++) {
        int ds = j >> 2, dh = (j >> 1) & 1, dw = j & 1;
        int gi = ((i1 * 2 + ds) * GH + (i2 * 2 + dh)) * GW + (i3 * 2 + dw);
        s += xg4[((size_t)(b * GN + gi)) * CDIM + c];
    }
    g[c] = s * (1.0f / W3G);
    __syncthreads();
    float aq = rq_b[c], ak = rk_b[c];
    for (int k = 0; k < CDIM; k++) { float gv = g[k]; aq = fmaf(gv, rq_w[k * CDIM + c], aq); ak = fmaf(gv, rk_w[k * CDIM + c], ak); }
    qh[(size_t)wid * CDIM + c] = aq;
    kh[(size_t)wid * CDIM + c] = ak;
}

// ---------------- K4b: top-k ----------------
__global__ void k_topk(const float* __restrict__ qh, const float* __restrict__ kh,
                       int* __restrict__ tidx) {
    int wid = blockIdx.x; int b = wid / NW;
    int m = threadIdx.x;
    __shared__ float q[CDIM];
    __shared__ float lv[NW];
    __shared__ int li[NW];
    if (m < CDIM) q[m] = qh[(size_t)wid * CDIM + m] * ROUTE_SCALE;
    __syncthreads();
    float acc = 0.f;
    const float* kr = kh + ((size_t)b * NW + m) * CDIM;
    for (int k = 0; k < CDIM; k++) acc = fmaf(q[k], kr[k], acc);
#pragma unroll
    for (int sel = 0; sel < TOPK; sel++) {
        lv[m] = acc; li[m] = m; __syncthreads();
#pragma unroll
        for (int s = 128; s > 0; s >>= 1) {
            if (m < s) {
                if (lv[m + s] > lv[m] || (lv[m + s] == lv[m] && li[m + s] < li[m])) {
                    lv[m] = lv[m + s]; li[m] = li[m + s];
                }
            }
            __syncthreads();
        }
        int best = li[0]; __syncthreads();
        if (m == best) acc = -1e30f;
        if (m == 0) tidx[wid * TOPK + sel] = best;
    }
}

// ---------------- K5a: LN local tokens -> lnsc bf16 ----------------
__global__ __launch_bounds__(256) void k_lnsc_local(const float* __restrict__ x_in,
        const float* __restrict__ ln_g, const float* __restrict__ ln_b,
        unsigned short* __restrict__ lnsc) {
    int blk = blockIdx.x;
    int wt = blk & 1; int hh = (blk >> 1) & 31; int s = (blk >> 6) & 15; int b = blk >> 10;
    int w0 = wt * 16;
    int t = threadIdx.x;
    __shared__ float tile[16][132];
    {
        int c = t >> 1; int wq = (t & 1) * 8;
        const float* src = x_in + (((size_t)(b * 128 + c) * SS + s)) * 1024 + hh * 32 + w0 + wq;
        float4 v0 = *(const float4*)src;
        float4 v1 = *(const float4*)(src + 4);
        tile[wq + 0][c] = v0.x; tile[wq + 1][c] = v0.y; tile[wq + 2][c] = v0.z; tile[wq + 3][c] = v0.w;
        tile[wq + 4][c] = v1.x; tile[wq + 5][c] = v1.y; tile[wq + 6][c] = v1.z; tile[wq + 7][c] = v1.w;
    }
    __syncthreads();
    int w = t >> 4; int j = t & 15;
    float vals[8];
    float s1 = 0.f;
#pragma unroll
    for (int i = 0; i < 8; i++) { vals[i] = tile[w][j * 8 + i]; s1 += vals[i]; }
    s1 = shfl_sum16(s1);
    float mu = s1 * (1.0f / 128.0f);
    float s2 = 0.f;
#pragma unroll
    for (int i = 0; i < 8; i++) { float d = vals[i] - mu; s2 += d * d; }
    s2 = shfl_sum16(s2);
    float rs = rsqrtf(s2 * (1.0f / 128.0f) + LN_EPS);
    float4 g0 = *(const float4*)(ln_g + j * 8);
    float4 g1 = *(const float4*)(ln_g + j * 8 + 4);
    float4 b0 = *(const float4*)(ln_b + j * 8);
    float4 b1 = *(const float4*)(ln_b + j * 8 + 4);
    float gv[8] = { g0.x, g0.y, g0.z, g0.w, g1.x, g1.y, g1.z, g1.w };
    float bv[8] = { b0.x, b0.y, b0.z, b0.w, b1.x, b1.y, b1.z, b1.w };
    int ww = w0 + w;
    int n = (s >> 2) * 64 + (hh >> 2) * 8 + (ww >> 2);
    int slot = (s & 3) * 16 + (hh & 3) * 4 + (ww & 3);
    unsigned short* dst = lnsc + ((size_t)(b * NW + n) * W3 + slot) * 128 + j * 8;
    ushort4 u0, u1;
    u0.x = f2bf((vals[0] - mu) * rs * gv[0] + bv[0]);
    u0.y = f2bf((vals[1] - mu) * rs * gv[1] + bv[1]);
    u0.z = f2bf((vals[2] - mu) * rs * gv[2] + bv[2]);
    u0.w = f2bf((vals[3] - mu) * rs * gv[3] + bv[3]);
    u1.x = f2bf((vals[4] - mu) * rs * gv[4] + bv[4]);
    u1.y = f2bf((vals[5] - mu) * rs * gv[5] + bv[5]);
    u1.z = f2bf((vals[6] - mu) * rs * gv[6] + bv[6]);
    u1.w = f2bf((vals[7] - mu) * rs * gv[7] + bv[7]);
    *(ushort4*)dst = u0;
    *(ushort4*)(dst + 4) = u1;
}

// ---------------- K5b: LN gathered global tokens -> lnsc bf16 ----------------
__global__ __launch_bounds__(256) void k_lnsc_gath(const float* __restrict__ xg4,
        const int* __restrict__ tidx,
        const float* __restrict__ ln_g, const float* __restrict__ ln_b,
        unsigned short* __restrict__ lnsc) {
    int blk = blockIdx.x;
    int kk = blk & 3; int wn = blk >> 2;
    int b = wn >> 8;
    int g = tidx[wn * TOPK + kk];
    int gi1 = g >> 6, gi2 = (g >> 3) & 7, gi3 = g & 7;
    int t = threadIdx.x; int j = t >> 5, lj = t & 31;
    int ds = j >> 2, dh = (j >> 1) & 1, dw = j & 1;
    int gi = ((gi1 * 2 + ds) * GH + (gi2 * 2 + dh)) * GW + (gi3 * 2 + dw);
    float4 v = *(const float4*)(xg4 + ((size_t)(b * GN + gi)) * 128 + lj * 4);
    float s1 = shfl_sum32(v.x + v.y + v.z + v.w);
    float mu = s1 * (1.0f / 128.0f);
    float d0 = v.x - mu, d1 = v.y - mu, d2 = v.z - mu, d3 = v.w - mu;
    float s2 = shfl_sum32(d0 * d0 + d1 * d1 + d2 * d2 + d3 * d3);
    float rs = rsqrtf(s2 * (1.0f / 128.0f) + LN_EPS);
    float4 g4 = *(const float4*)(ln_g + lj * 4);
    float4 b4 = *(const float4*)(ln_b + lj * 4);
    ushort4 u;
    u.x = f2bf(d0 * rs * g4.x + b4.x);
    u.y = f2bf(d1 * rs * g4.y + b4.y);
    u.z = f2bf(d2 * rs * g4.z + b4.z);
    u.w = f2bf(d3 * rs * g4.w + b4.w);
    *(ushort4*)(lnsc + ((size_t)wn * W3 + 64 + kk * 8 + j) * 128 + lj * 4) = u;
}

// ---------------- K6: local attention via MFMA (r7 best-measured variant) ----------------
__global__ __launch_bounds__(256) void k_local_mfma(const unsigned short* __restrict__ lnsc,
        const unsigned short* __restrict__ wt, const float* __restrict__ gqkv_b,
        float* __restrict__ aout) {
    int wn = blockIdx.x;
    int t = threadIdx.x; int w = t >> 6; int lane = t & 63;
    int l15 = lane & 15, quad = lane >> 4;
    __shared__ __align__(16) unsigned short Qs[64 * 136];
    __shared__ __align__(16) unsigned short Ks2[96 * 136];
    __shared__ __align__(16) unsigned short Vts[128 * 104];
    __shared__ __align__(16) unsigned short Ps[4][16 * 40];

    const unsigned short* Xb = lnsc + (size_t)wn * W3 * 128;
    f32x4 zero4 = {0.f, 0.f, 0.f, 0.f};

    for (int mt = 0; mt < 4; mt++) {
        bshort8 a[4];
#pragma unroll
        for (int ks = 0; ks < 4; ks++)
            a[ks] = *(const bshort8*)(Xb + (mt * 16 + l15) * 128 + ks * 32 + quad * 8);
#pragma unroll
        for (int which = 0; which < 2; which++) {
            int n0 = (w + which * 4) * 16;
            f32x4 acc = zero4;
#pragma unroll
            for (int ks = 0; ks < 4; ks++) {
                bshort8 bfr = *(const bshort8*)(wt + (n0 + l15) * 128 + ks * 32 + quad * 8);
                acc = __builtin_amdgcn_mfma_f32_16x16x32_bf16(a[ks], bfr, acc, 0, 0, 0);
            }
            float bias = gqkv_b[n0 + l15] * ROUTE_SCALE;
#pragma unroll
            for (int r = 0; r < 4; r++)
                Qs[(mt * 16 + quad * 4 + r) * 136 + n0 + l15] = f2bf(acc[r] + bias);
        }
    }
    for (int mt = 0; mt < 6; mt++) {
        bshort8 a[4];
#pragma unroll
        for (int ks = 0; ks < 4; ks++)
            a[ks] = *(const bshort8*)(Xb + (mt * 16 + l15) * 128 + ks * 32 + quad * 8);
#pragma unroll
        for (int which = 0; which < 2; which++) {
            int nt8 = w + which * 4;
            int n0g = 128 + nt8 * 16;
            f32x4 acc = zero4;
#pragma unroll
            for (int ks = 0; ks < 4; ks++) {
                bshort8 bfr = *(const bshort8*)(wt + (n0g + l15) * 128 + ks * 32 + quad * 8);
                acc = __builtin_amdgcn_mfma_f32_16x16x32_bf16(a[ks], bfr, acc, 0, 0, 0);
            }
            float bias = gqkv_b[n0g + l15];
#pragma unroll
            for (int r = 0; r < 4; r++)
                Ks2[(mt * 16 + quad * 4 + r) * 136 + nt8 * 16 + l15] = f2bf(acc[r] + bias);
        }
    }
    for (int which = 0; which < 2; which++) {
        int mtv = 2 * w + which;
        bshort8 a[4];
#pragma unroll
        for (int ks = 0; ks < 4; ks++)
            a[ks] = *(const bshort8*)(wt + (256 + mtv * 16 + l15) * 128 + ks * 32 + quad * 8);
        float biasr[4];
#pragma unroll
        for (int r = 0; r < 4; r++) biasr[r] = gqkv_b[256 + mtv * 16 + quad * 4 + r];
        for (int ntv = 0; ntv < 6; ntv++) {
            f32x4 acc = zero4;
#pragma unroll
            for (int ks = 0; ks < 4; ks++) {
                bshort8 bfr = *(const bshort8*)(Xb + (ntv * 16 + l15) * 128 + ks * 32 + quad * 8);
                acc = __builtin_amdgcn_mfma_f32_16x16x32_bf16(a[ks], bfr, acc, 0, 0, 0);
            }
#pragma unroll
            for (int r = 0; r < 4; r++)
                Vts[(mtv * 16 + quad * 4 + r) * 104 + ntv * 16 + l15] = f2bf(acc[r] + biasr[r]);
        }
    }
    __syncthreads();

    unsigned short* Pw = &Ps[w][0];
    bshort8 zfrag = {0, 0, 0, 0, 0, 0, 0, 0};
#pragma unroll
    for (int hh2 = 0; hh2 < 2; hh2++) {
        int h = 2 * w + hh2;
        for (int mt = 0; mt < 4; mt++) {
            bshort8 aq = zfrag;
            if (quad < 2)
                aq = *(const bshort8*)(Qs + (mt * 16 + l15) * 136 + h * 16 + quad * 8);
            float rsum[4] = {0.f, 0.f, 0.f, 0.f};
            f32x4 oacc = zero4;
#pragma unroll
            for (int kc = 0; kc < 96; kc += 32) {
#pragma unroll
                for (int sub = 0; sub < 2; sub++) {
                    int nt = (kc >> 4) + sub;
                    bshort8 bk = zfrag;
                    if (quad < 2)
                        bk = *(const bshort8*)(Ks2 + (nt * 16 + l15) * 136 + h * 16 + quad * 8);
                    f32x4 s = __builtin_amdgcn_mfma_f32_16x16x32_bf16(aq, bk, zero4, 0, 0, 0);
#pragma unroll
                    for (int r = 0; r < 4; r++) {
                        float p = __expf(s[r]);
                        rsum[r] += p;
                        Pw[(quad * 4 + r) * 40 + sub * 16 + l15] = f2bf(p);
                    }
                }
                bshort8 ap = *(const bshort8*)(Pw + l15 * 40 + quad * 8);
                bshort8 bv = *(const bshort8*)(Vts + (h * 16 + l15) * 104 + kc + quad * 8);
                oacc = __builtin_amdgcn_mfma_f32_16x16x32_bf16(ap, bv, oacc, 0, 0, 0);
            }
#pragma unroll
            for (int r = 0; r < 4; r++) {
                float v = rsum[r];
                v += __shfl_xor(v, 1); v += __shfl_xor(v, 2);
                v += __shfl_xor(v, 4); v += __shfl_xor(v, 8);
                rsum[r] = v;
            }
#pragma unroll
            for (int r = 0; r < 4; r++)
                aout[((size_t)wn * W3L + mt * 16 + quad * 4 + r) * 128 + h * 16 + l15]
                    = oacc[r] / rsum[r];
        }
    }
}

// ---------------- K7: wo projection + shortcut via MFMA, 32 spatial tokens/block ----------------
__global__ __launch_bounds__(256) void k_wo_mfma(const float* __restrict__ aout,
        const unsigned short* __restrict__ wot, const float* __restrict__ wo_b,
        const float* __restrict__ x_in, float* __restrict__ lpre) {
    int blk = blockIdx.x; int T0 = blk * 32;
    int b = T0 >> 14; int sp0 = T0 & 16383;
    int t = threadIdx.x; int w = t >> 6; int lane = t & 63;
    int l15 = lane & 15, quad = lane >> 4;
    __shared__ __align__(16) unsigned short as2[32 * 136];
    __shared__ __align__(16) float xs[32 * 132];
    f32x4 zero4 = {0.f, 0.f, 0.f, 0.f};

    {
        int j = t >> 3, p = t & 7, c0 = p * 16;
        int sp = sp0 + j;
        int s = sp >> 10, hh = (sp >> 5) & 31, ww = sp & 31;
        int n = (s >> 2) * 64 + (hh >> 2) * 8 + (ww >> 2);
        int slot = (s & 3) * 16 + (hh & 3) * 4 + (ww & 3);
        const float* src = aout + (((size_t)(b * NW + n)) * W3L + slot) * 128 + c0;
#pragma unroll
        for (int i4 = 0; i4 < 4; i4++) {
            float4 v = *(const float4*)(src + i4 * 4);
            ushort4 u = { f2bf(v.x), f2bf(v.y), f2bf(v.z), f2bf(v.w) };
            *(ushort4*)&as2[j * 136 + c0 + i4 * 4] = u;
        }
    }
    {
        int c = t >> 1, half = t & 1, j0 = half * 16;
        const float* src = x_in + ((size_t)(b * 128 + c)) * 16384 + sp0 + j0;
#pragma unroll
        for (int i4 = 0; i4 < 4; i4++) {
            float4 v = *(const float4*)(src + i4 * 4);
            xs[(j0 + i4 * 4 + 0) * 132 + c] = v.x;
            xs[(j0 + i4 * 4 + 1) * 132 + c] = v.y;
            xs[(j0 + i4 * 4 + 2) * 132 + c] = v.z;
            xs[(j0 + i4 * 4 + 3) * 132 + c] = v.w;
        }
    }
    __syncthreads();

    bshort8 a[2][4];
#pragma unroll
    for (int mt = 0; mt < 2; mt++)
#pragma unroll
        for (int ks = 0; ks < 4; ks++)
            a[mt][ks] = *(const bshort8*)(as2 + (mt * 16 + l15) * 136 + ks * 32 + quad * 8);
#pragma unroll
    for (int nt = 0; nt < 2; nt++) {
        int n0 = w * 32 + nt * 16;
        f32x4 acc0 = zero4, acc1 = zero4;
#pragma unroll
        for (int ks = 0; ks < 4; ks++) {
            bshort8 bfr = *(const bshort8*)(wot + (n0 + l15) * 128 + ks * 32 + quad * 8);
            acc0 = __builtin_amdgcn_mfma_f32_16x16x32_bf16(a[0][ks], bfr, acc0, 0, 0, 0);
            acc1 = __builtin_amdgcn_mfma_f32_16x16x32_bf16(a[1][ks], bfr, acc1, 0, 0, 0);
        }
        float bias = wo_b[n0 + l15];
#pragma unroll
        for (int r = 0; r < 4; r++) {
            int m0 = quad * 4 + r;
            int m1 = 16 + quad * 4 + r;
            lpre[((size_t)T0 + m0) * 128 + n0 + l15] = acc0[r] + bias + xs[m0 * 132 + n0 + l15];
            lpre[((size_t)T0 + m1) * 128 + n0 + l15] = acc1[r] + bias + xs[m1 * 132 + n0 + l15];
        }
    }
}

// ---------------- K8: LN + MLP2 via MFMA, 32 tokens/block, single aliased LDS buffer ----------------
__global__ __launch_bounds__(256) void k_mlp2_mfma(const float* __restrict__ lpre,
        const float* __restrict__ ln_g, const float* __restrict__ ln_b,
        const unsigned short* __restrict__ w1t, const float* __restrict__ b1,
        const unsigned short* __restrict__ w2t, const float* __restrict__ b2,
        float* __restrict__ lout) {
    int blk = blockIdx.x;
    int T0 = blk * 32;
    int b = T0 >> 14;
    int sp = T0 & 16383;
    int t = threadIdx.x; int w = t >> 6; int lane = t & 63;
    int l15 = lane & 15, quad = lane >> 4;
    __shared__ __align__(16) unsigned short buf[32 * 520];
    float* of32 = (float*)buf;

    {
        int j = t >> 3, p = t & 7, c0 = p * 16;
        const float* src = lpre + ((size_t)T0 + j) * 128 + c0;
        float4 v0 = *(const float4*)(src + 0);
        float4 v1 = *(const float4*)(src + 4);
        float4 v2 = *(const float4*)(src + 8);
        float4 v3 = *(const float4*)(src + 12);
        float s1 = (v0.x + v0.y + v0.z + v0.w) + (v1.x + v1.y + v1.z + v1.w)
                 + (v2.x + v2.y + v2.z + v2.w) + (v3.x + v3.y + v3.z + v3.w);
        s1 = shfl_sum8(s1);
        float mu = s1 * (1.0f / 128.0f);
        float vv[16] = { v0.x, v0.y, v0.z, v0.w, v1.x, v1.y, v1.z, v1.w,
                         v2.x, v2.y, v2.z, v2.w, v3.x, v3.y, v3.z, v3.w };
        float s2 = 0.f;
#pragma unroll
        for (int i = 0; i < 16; i++) { float d = vv[i] - mu; s2 += d * d; }
        s2 = shfl_sum8(s2);
        float rs = rsqrtf(s2 * (1.0f / 128.0f) + LN_EPS);
        unsigned short hb[16];
#pragma unroll
        for (int i4 = 0; i4 < 4; i4++) {
            float4 g4 = *(const float4*)(ln_g + c0 + i4 * 4);
            float4 b4 = *(const float4*)(ln_b + c0 + i4 * 4);
            hb[i4 * 4 + 0] = f2bf((vv[i4 * 4 + 0] - mu) * rs * g4.x + b4.x);
            hb[i4 * 4 + 1] = f2bf((vv[i4 * 4 + 1] - mu) * rs * g4.y + b4.y);
            hb[i4 * 4 + 2] = f2bf((vv[i4 * 4 + 2] - mu) * rs * g4.z + b4.z);
            hb[i4 * 4 + 3] = f2bf((vv[i4 * 4 + 3] - mu) * rs * g4.w + b4.w);
        }
        *(ushort4*)&buf[j * 136 + c0 + 0] = *(ushort4*)&hb[0];
        *(ushort4*)&buf[j * 136 + c0 + 4] = *(ushort4*)&hb[4];
        *(ushort4*)&buf[j * 136 + c0 + 8] = *(ushort4*)&hb[8];
        *(ushort4*)&buf[j * 136 + c0 + 12] = *(ushort4*)&hb[12];
    }
    __syncthreads();

    bshort8 a1[2][4];
#pragma unroll
    for (int mt = 0; mt < 2; mt++)
#pragma unroll
        for (int ks = 0; ks < 4; ks++)
            a1[mt][ks] = *(const bshort8*)(buf + (mt * 16 + l15) * 136 + ks * 32 + quad * 8);
    __syncthreads();

    f32x4 zero4 = {0.f, 0.f, 0.f, 0.f};
    {
        int n0w = w * 128;
#pragma unroll
        for (int nt = 0; nt < 8; nt++) {
            int n0 = n0w + nt * 16;
            f32x4 acc0 = zero4, acc1 = zero4;
#pragma unroll
            for (int ks = 0; ks < 4; ks++) {
                bshort8 bfr = *(const bshort8*)(w1t + (size_t)(n0 + l15) * 128 + ks * 32 + quad * 8);
                acc0 = __builtin_amdgcn_mfma_f32_16x16x32_bf16(a1[0][ks], bfr, acc0, 0, 0, 0);
                acc1 = __builtin_amdgcn_mfma_f32_16x16x32_bf16(a1[1][ks], bfr, acc1, 0, 0, 0);
            }
            float bias = b1[n0 + l15];
#pragma unroll
            for (int r = 0; r < 4; r++) {
                buf[(quad * 4 + r) * 520 + n0 + l15] = f2bf(gelu_exact(acc0[r] + bias));
                buf[(16 + quad * 4 + r) * 520 + n0 + l15] = f2bf(gelu_exact(acc1[r] + bias));
            }
        }
    }
    __syncthreads();

    f32x4 acc[2][2];
    acc[0][0] = zero4; acc[0][1] = zero4; acc[1][0] = zero4; acc[1][1] = zero4;
    {
#pragma unroll 4
        for (int ks = 0; ks < 16; ks++) {
            bshort8 a0 = *(const bshort8*)(buf + (l15) * 520 + ks * 32 + quad * 8);
            bshort8 a1b = *(const bshort8*)(buf + (16 + l15) * 520 + ks * 32 + quad * 8);
#pragma unroll
            for (int nt = 0; nt < 2; nt++) {
                int n0 = w * 32 + nt * 16;
                bshort8 bfr = *(const bshort8*)(w2t + (size_t)(n0 + l15) * 512 + ks * 32 + quad * 8);
                acc[0][nt] = __builtin_amdgcn_mfma_f32_16x16x32_bf16(a0, bfr, acc[0][nt], 0, 0, 0);
                acc[1][nt] = __builtin_amdgcn_mfma_f32_16x16x32_bf16(a1b, bfr, acc[1][nt], 0, 0, 0);
            }
        }
    }
    __syncthreads();

#pragma unroll
    for (int mt = 0; mt < 2; mt++) {
#pragma unroll
        for (int nt = 0; nt < 2; nt++) {
            int n0 = w * 32 + nt * 16;
            float bias = b2[n0 + l15];
#pragma unroll
            for (int r = 0; r < 4; r++) {
                int m = mt * 16 + quad * 4 + r;
                float res = lpre[((size_t)T0 + m) * 128 + n0 + l15];
                of32[m * 132 + n0 + l15] = res + acc[mt][nt][r] + bias;
            }
        }
    }
    __syncthreads();

    {
        int c = t >> 1, half = t & 1, j0 = half * 16;
        float* dst = lout + ((size_t)(b * 128 + c)) * NSP + sp + j0;
#pragma unroll
        for (int i4 = 0; i4 < 4; i4++) {
            float4 ov = { of32[(j0 + i4 * 4 + 0) * 132 + c], of32[(j0 + i4 * 4 + 1) * 132 + c],
                          of32[(j0 + i4 * 4 + 2) * 132 + c], of32[(j0 + i4 * 4 + 3) * 132 + c] };
            *(float4*)(dst + i4 * 4) = ov;
        }
    }
}

extern "C" void kernel_launch(void* const* d_in, const int* in_sizes, int n_in,
                              void* d_out, int out_size, void* d_ws, size_t ws_size,
                              hipStream_t stream) {
    const float* x_in   = (const float*)d_in[0];
    const float* xg_in  = (const float*)d_in[1];
    const float* qkv_w  = (const float*)d_in[2];
    const float* qkv_b  = (const float*)d_in[3];
    const float* proj_w = (const float*)d_in[4];
    const float* proj_b = (const float*)d_in[5];
    const float* ln_g   = (const float*)d_in[6];
    const float* ln_b   = (const float*)d_in[7];
    const float* mlp_w1 = (const float*)d_in[8];
    const float* mlp_b1 = (const float*)d_in[9];
    const float* mlp_w2 = (const float*)d_in[10];
    const float* mlp_b2 = (const float*)d_in[11];
    const float* rq_w   = (const float*)d_in[12];
    const float* rq_b   = (const float*)d_in[13];
    const float* rk_w   = (const float*)d_in[14];
    const float* rk_b   = (const float*)d_in[15];
    const float* gqkv_w = (const float*)d_in[16];
    const float* gqkv_b = (const float*)d_in[17];
    const float* wo_w   = (const float*)d_in[18];
    const float* wo_b   = (const float*)d_in[19];
    const float* m2_w1  = (const float*)d_in[20];
    const float* m2_b1  = (const float*)d_in[21];
    const float* m2_w2  = (const float*)d_in[22];
    const float* m2_b2  = (const float*)d_in[23];

    float* out = (float*)d_out;
    float* ws  = (float*)d_ws;

    float* xg4 = ws;                                         // 524288
    float* xg  = ws + 524288;                                // 524288
    unsigned short* qgb  = (unsigned short*)(ws + 1048576);  // 524288 bf16
    unsigned short* kgb  = (unsigned short*)(ws + 1310720);  // 524288 bf16
    unsigned short* vgtb = (unsigned short*)(ws + 1572864);  // 524288 bf16 (V^T)
    float* og  = ws + 1835008;                               // 524288
    float* qh  = ws + 2359296;                               // 65536
    float* kh  = ws + 2424832;                               // 65536
    int*   tidx = (int*)(ws + 2490368);                      // 2048
    unsigned short* lnsc = (unsigned short*)(ws + 2492416);  // 6291456 bf16
    float* aout = ws + 2492416 + 3145728;                    // 4194304
    float* lpre = ws + 9832448;                              // 4194304
    unsigned short* wt   = (unsigned short*)(ws + 14026752); // 49152 bf16
    unsigned short* w1t  = (unsigned short*)(ws + 14051328); // 65536 bf16
    unsigned short* w2t  = (unsigned short*)(ws + 14084096); // 65536 bf16
    unsigned short* projt = (unsigned short*)(ws + 14116864); // 16384 bf16
    unsigned short* gw1t  = (unsigned short*)(ws + 14125056); // 65536 bf16
    unsigned short* gw2t  = (unsigned short*)(ws + 14157824); // 65536 bf16
    unsigned short* wot   = (unsigned short*)(ws + 14190592); // 16384 bf16
    unsigned short* qkvt  = (unsigned short*)(ws + 14198784); // 49152 bf16

    const size_t L_OUT = (size_t)BATCH * CDIM * NSP;
    float* gout = out + L_OUT;

    hipLaunchKernelGGL(k_wprep_all, dim3(1536), dim3(256), 0, stream,
                       gqkv_w, m2_w1, m2_w2, proj_w, mlp_w1, mlp_w2, wo_w, qkv_w,
                       wt, w1t, w2t, projt, gw1t, gw2t, wot, qkvt);
    hipLaunchKernelGGL(k_gqkv_mfma, dim3(256), dim3(256), 0, stream,
                       xg_in, qkvt, qkv_b, ln_g, ln_b, xg, qgb, kgb, vgtb);
    hipLaunchKernelGGL(k_gattn_mfma, dim3(2048), dim3(256), 0, stream, qgb, kgb, vgtb, og);
    hipLaunchKernelGGL(k_gmlp_mfma, dim3(256), dim3(256), 0, stream,
                       og, xg, projt, proj_b, ln_g, ln_b, gw1t, mlp_b1, gw2t, mlp_b2,
                       xg4, gout);
    hipLaunchKernelGGL(k_routing_qk, dim3(512), dim3(128), 0, stream,
                       xg4, rq_w, rq_b, rk_w, rk_b, qh, kh);
    hipLaunchKernelGGL(k_topk, dim3(512), dim3(256), 0, stream, qh, kh, tidx);
    hipLaunchKernelGGL(k_lnsc_local, dim3(2048), dim3(256), 0, stream,
                       x_in, ln_g, ln_b, lnsc);
    hipLaunchKernelGGL(k_lnsc_gath, dim3(2048), dim3(256), 0, stream,
                       xg4, tidx, ln_g, ln_b, lnsc);
    hipLaunchKernelGGL(k_local_mfma, dim3(512), dim3(256), 0, stream,
                       lnsc, wt, gqkv_b, aout);
    hipLaunchKernelGGL(k_wo_mfma, dim3(1024), dim3(256), 0, stream,
                       aout, wot, wo_b, x_in, lpre);
    hipLaunchKernelGGL(k_mlp2_mfma, dim3(1024), dim3(256), 0, stream,
                       lpre, ln_g, ln_b, w1t, m2_b1, w2t, m2_b2, out);
}